// Round 1
// baseline (516.740 us; speedup 1.0000x reference)
//
#include <hip/hip_runtime.h>
#include <hip/hip_bf16.h>

typedef __attribute__((ext_vector_type(8))) __bf16 bf16x8;
typedef __attribute__((ext_vector_type(4))) float f32x4;

#define DEV static __device__ __forceinline__

DEV unsigned short f2bf(float f) {
  union { float f; unsigned int u; } v; v.f = f;
  unsigned int u = v.u;
  unsigned int r = (u + 0x7fffu + ((u >> 16) & 1u)) >> 16;
  return (unsigned short)r;
}
DEV float bf2f(unsigned short h) {
  union { unsigned int u; float f; } v; v.u = ((unsigned int)h) << 16;
  return v.f;
}
DEV f32x4 mfma16(bf16x8 a, bf16x8 b, f32x4 c) {
  return __builtin_amdgcn_mfma_f32_16x16x32_bf16(a, b, c, 0, 0, 0);
}
DEV void gload_lds16(const void* g, void* l) {
  __builtin_amdgcn_global_load_lds((__attribute__((address_space(1))) void*)g,
                                   (__attribute__((address_space(3))) void*)l,
                                   16, 0, 0);
}

// ---------------- f32 -> bf16 convert ----------------
__global__ __launch_bounds__(256) void cvt_k(const float* __restrict__ in,
                                             unsigned short* __restrict__ out, int n) {
  int i = (blockIdx.x * 256 + threadIdx.x) * 4;
  if (i + 3 < n) {
    float4 v = *(const float4*)(in + i);
    out[i + 0] = f2bf(v.x);
    out[i + 1] = f2bf(v.y);
    out[i + 2] = f2bf(v.z);
    out[i + 3] = f2bf(v.w);
  }
}

// ---------------- RMSNorm: fp32 in -> bf16 out (D=1024) ----------------
__global__ __launch_bounds__(256) void rmsnorm_k(const float* __restrict__ x,
                                                 const float* __restrict__ w,
                                                 unsigned short* __restrict__ out) {
  int row = blockIdx.x;
  int tid = threadIdx.x;
  const float* xr = x + (size_t)row * 1024;
  float4 v = *(const float4*)(xr + tid * 4);
  float ss = v.x * v.x + v.y * v.y + v.z * v.z + v.w * v.w;
#pragma unroll
  for (int m = 32; m >= 1; m >>= 1) ss += __shfl_xor(ss, m);
  __shared__ float red[4];
  int wid = tid >> 6;
  if ((tid & 63) == 0) red[wid] = ss;
  __syncthreads();
  float tot = red[0] + red[1] + red[2] + red[3];
  float rs = rsqrtf(tot * (1.0f / 1024.0f) + 1e-5f);
  float4 wv = *(const float4*)(w + tid * 4);
  unsigned short* o = out + (size_t)row * 1024 + tid * 4;
  o[0] = f2bf(v.x * rs * wv.x);
  o[1] = f2bf(v.y * rs * wv.y);
  o[2] = f2bf(v.z * rs * wv.z);
  o[3] = f2bf(v.w * rs * wv.w);
}

// ---------------- RoPE in-place on [BH=32][S=2048][64] bf16 ----------------
__global__ __launch_bounds__(256) void rope_k(unsigned short* __restrict__ x,
                                              const int* __restrict__ pos) {
  int idx = blockIdx.x * 256 + threadIdx.x;  // B*H*S*32 = 2,097,152 threads
  int i = idx & 31;
  int s = (idx >> 5) & 2047;
  int bh = idx >> 16;
  int b = bh >> 4;
  float p = (float)pos[b * 2048 + s];
  // inv_freq = 10000^(-i/32) = exp2(-i * log2(10000)/32)
  float inv = exp2f(-(float)i * 0.4152410118609203f);
  float ang = p * inv;
  float sn = sinf(ang), cs = cosf(ang);
  size_t base = (((size_t)bh * 2048) + s) * 64 + 2 * i;
  float x1 = bf2f(x[base]), x2 = bf2f(x[base + 1]);
  x[base]     = f2bf(x1 * cs - x2 * sn);
  x[base + 1] = f2bf(x1 * sn + x2 * cs);
}

// ---------------- GEMM: C[M,N] = A[M,K](bf16) * Bw[N,K]^T(bf16) ----------------
// MODE 0: store bf16 C[m*N+n]
// MODE 1: QKV scatter bf16 -> [b][h][s][d]  (m=b*2048+s, n=h*64+d)
// MODE 2: outf[m*N+n] = resid[m*N+n] + acc   (fp32)
// MODE 3: outb[m*N+n] = silu(gate[m*N+n]) * acc  (bf16)
template <int MODE>
__global__ __launch_bounds__(256) void gemm_bt(const unsigned short* __restrict__ A,
                                               const unsigned short* __restrict__ Bw,
                                               int K, int N,
                                               unsigned short* __restrict__ outb,
                                               float* __restrict__ outf,
                                               const float* __restrict__ resid,
                                               const unsigned short* __restrict__ gate) {
  __shared__ unsigned short As[128 * 64];
  __shared__ unsigned short Bs[128 * 64];
  const int tid = threadIdx.x;
  const int wid = tid >> 6, lane = tid & 63;
  const int wr = wid >> 1, wc = wid & 1;
  const int m0 = blockIdx.x * 128, n0 = blockIdx.y * 128;
  f32x4 acc[4][4] = {};

  for (int k0 = 0; k0 < K; k0 += 64) {
    __syncthreads();  // previous-iter LDS reads done before overwrite
#pragma unroll
    for (int it = 0; it < 4; ++it) {
      int c = wid * 4 + it;              // 16 chunks of 1024B
      int row = c * 8 + (lane >> 3);
      int col = (lane & 7) * 8;
      gload_lds16(A + (size_t)(m0 + row) * K + k0 + col, As + c * 512);
      gload_lds16(Bw + (size_t)(n0 + row) * K + k0 + col, Bs + c * 512);
    }
    asm volatile("s_waitcnt vmcnt(0)" ::: "memory");
    __syncthreads();
#pragma unroll
    for (int kk = 0; kk < 2; ++kk) {
      const int kof = kk * 32 + (lane >> 4) * 8;
      bf16x8 af[4], bfr[4];
#pragma unroll
      for (int i = 0; i < 4; ++i) {
        af[i]  = *(const bf16x8*)(As + (wr * 64 + i * 16 + (lane & 15)) * 64 + kof);
        bfr[i] = *(const bf16x8*)(Bs + (wc * 64 + i * 16 + (lane & 15)) * 64 + kof);
      }
#pragma unroll
      for (int i = 0; i < 4; ++i)
#pragma unroll
        for (int j = 0; j < 4; ++j) acc[i][j] = mfma16(af[i], bfr[j], acc[i][j]);
    }
  }

  const int rb = m0 + wr * 64 + ((lane >> 4) * 4);
  const int cb = n0 + wc * 64 + (lane & 15);
#pragma unroll
  for (int i = 0; i < 4; ++i) {
#pragma unroll
    for (int r = 0; r < 4; ++r) {
      int m = rb + i * 16 + r;
#pragma unroll
      for (int j = 0; j < 4; ++j) {
        int n = cb + j * 16;
        float val = acc[i][j][r];
        if (MODE == 0) {
          outb[(size_t)m * N + n] = f2bf(val);
        } else if (MODE == 1) {
          int b = m >> 11, s = m & 2047, hh = n >> 6, dd = n & 63;
          outb[(((size_t)b * 16 + hh) * 2048 + s) * 64 + dd] = f2bf(val);
        } else if (MODE == 2) {
          size_t idx = (size_t)m * N + n;
          outf[idx] = resid[idx] + val;
        } else {
          size_t idx = (size_t)m * N + n;
          float gv = bf2f(gate[idx]);
          float sg = gv / (1.0f + __expf(-gv));
          outb[idx] = f2bf(sg * val);
        }
      }
    }
  }
}

// ---------------- Flash attention: q,k,v [BH][S][64] bf16 -> ctx [B][S][1024] bf16 ----------------
__global__ __launch_bounds__(256) void attn_k(const unsigned short* __restrict__ q,
                                              const unsigned short* __restrict__ k,
                                              const unsigned short* __restrict__ v,
                                              unsigned short* __restrict__ ctx) {
  __shared__ unsigned short Ks[64 * 64];
  __shared__ unsigned short Vs[64 * 64];
  __shared__ unsigned short Ps[4][16 * 64];
  const int qt = blockIdx.x, bh = blockIdx.y;
  const int tid = threadIdx.x, wid = tid >> 6, lane = tid & 63;
  const int q0 = qt * 64;
  const size_t bhS = (size_t)bh * 2048;

  bf16x8 qf[2];
  {
    const unsigned short* qp = q + (bhS + q0 + wid * 16 + (lane & 15)) * 64 + (lane >> 4) * 8;
    qf[0] = *(const bf16x8*)qp;
    qf[1] = *(const bf16x8*)(qp + 32);
  }
  float mrow[4], lrow[4];
  f32x4 o[4] = {};
#pragma unroll
  for (int r = 0; r < 4; ++r) { mrow[r] = -1e30f; lrow[r] = 0.0f; }
  const int rowb = q0 + wid * 16 + ((lane >> 4) * 4);

  for (int kt = 0; kt <= qt; ++kt) {
    __syncthreads();
#pragma unroll
    for (int it = 0; it < 2; ++it) {
      int c = wid * 2 + it;  // 8 chunks of 1024B
      int row = c * 8 + (lane >> 3);
      int col = (lane & 7) * 8;
      size_t gsrc = (bhS + kt * 64 + row) * 64 + col;
      gload_lds16(k + gsrc, Ks + c * 512);
      gload_lds16(v + gsrc, Vs + c * 512);
    }
    asm volatile("s_waitcnt vmcnt(0)" ::: "memory");
    __syncthreads();

    // S = Q K^T  (16 q-rows x 64 keys per wave)
    f32x4 s[4];
#pragma unroll
    for (int nt = 0; nt < 4; ++nt) {
      f32x4 z = {};
#pragma unroll
      for (int ks = 0; ks < 2; ++ks) {
        bf16x8 kf = *(const bf16x8*)(Ks + (nt * 16 + (lane & 15)) * 64 + ks * 32 + (lane >> 4) * 8);
        z = mfma16(qf[ks], kf, z);
      }
      s[nt] = z;
    }
    const bool diag = (kt == qt);
#pragma unroll
    for (int r = 0; r < 4; ++r) {
      float mx = -1e30f;
#pragma unroll
      for (int nt = 0; nt < 4; ++nt) {
        float val = s[nt][r] * 0.125f;
        if (diag && (kt * 64 + nt * 16 + (lane & 15)) > (rowb + r)) val = -1e30f;
        s[nt][r] = val;
        mx = fmaxf(mx, val);
      }
      mx = fmaxf(mx, __shfl_xor(mx, 1));
      mx = fmaxf(mx, __shfl_xor(mx, 2));
      mx = fmaxf(mx, __shfl_xor(mx, 4));
      mx = fmaxf(mx, __shfl_xor(mx, 8));
      float mnew = fmaxf(mrow[r], mx);
      float sum = 0.0f;
#pragma unroll
      for (int nt = 0; nt < 4; ++nt) {
        float p = __expf(s[nt][r] - mnew);
        s[nt][r] = p;
        sum += p;
      }
      sum += __shfl_xor(sum, 1);
      sum += __shfl_xor(sum, 2);
      sum += __shfl_xor(sum, 4);
      sum += __shfl_xor(sum, 8);
      float alpha = __expf(mrow[r] - mnew);
      lrow[r] = lrow[r] * alpha + sum;
      mrow[r] = mnew;
#pragma unroll
      for (int d = 0; d < 4; ++d) o[d][r] *= alpha;
    }
    // P -> LDS (per-wave private region), then PV
#pragma unroll
    for (int nt = 0; nt < 4; ++nt)
#pragma unroll
      for (int r = 0; r < 4; ++r)
        Ps[wid][((lane >> 4) * 4 + r) * 64 + nt * 16 + (lane & 15)] = f2bf(s[nt][r]);
    __syncthreads();
#pragma unroll
    for (int ks = 0; ks < 2; ++ks) {
      bf16x8 pf = *(const bf16x8*)(&Ps[wid][(lane & 15) * 64 + ks * 32 + (lane >> 4) * 8]);
#pragma unroll
      for (int d = 0; d < 4; ++d) {
        bf16x8 vf;
#pragma unroll
        for (int j = 0; j < 8; ++j)
          ((unsigned short*)&vf)[j] = Vs[(ks * 32 + (lane >> 4) * 8 + j) * 64 + d * 16 + (lane & 15)];
        o[d] = mfma16(pf, vf, o[d]);
      }
    }
  }
  const int b = bh >> 4, hh = bh & 15;
#pragma unroll
  for (int d = 0; d < 4; ++d)
#pragma unroll
    for (int r = 0; r < 4; ++r) {
      float val = o[d][r] / lrow[r];
      ctx[((size_t)b * 2048 + (rowb + r)) * 1024 + hh * 64 + d * 16 + (lane & 15)] = f2bf(val);
    }
}

extern "C" void kernel_launch(void* const* d_in, const int* in_sizes, int n_in,
                              void* d_out, int out_size, void* d_ws, size_t ws_size,
                              hipStream_t stream) {
  (void)in_sizes; (void)n_in; (void)out_size; (void)ws_size;
  const float* in_f = (const float*)d_in[0];
  const int* pos    = (const int*)d_in[1];
  const float* q_w  = (const float*)d_in[2];
  const float* k_w  = (const float*)d_in[3];
  const float* v_w  = (const float*)d_in[4];
  const float* o_w  = (const float*)d_in[5];
  const float* ln1  = (const float*)d_in[6];
  const float* ln2  = (const float*)d_in[7];
  const float* w1   = (const float*)d_in[8];
  const float* w2   = (const float*)d_in[9];
  const float* w3   = (const float*)d_in[10];
  float* out = (float*)d_out;

  unsigned short* ws = (unsigned short*)d_ws;
  size_t off = 0;
  auto alloc = [&](size_t n) { unsigned short* p = ws + off; off += n; return p; };
  unsigned short* wqb = alloc(1048576);
  unsigned short* wkb = alloc(1048576);
  unsigned short* wvb = alloc(1048576);
  unsigned short* wob = alloc(1048576);
  unsigned short* w1b = alloc(4194304);
  unsigned short* w2b = alloc(4194304);
  unsigned short* w3b = alloc(4194304);
  unsigned short* xn  = alloc(4194304);   // reused for xn2
  unsigned short* qb  = alloc(4194304);
  unsigned short* kb  = alloc(4194304);
  unsigned short* vb  = alloc(4194304);
  unsigned short* cx  = alloc(4194304);
  unsigned short* gb  = alloc(16777216);
  unsigned short* hb  = alloc(16777216);

  cvt_k<<<1024, 256, 0, stream>>>(q_w, wqb, 1048576);
  cvt_k<<<1024, 256, 0, stream>>>(k_w, wkb, 1048576);
  cvt_k<<<1024, 256, 0, stream>>>(v_w, wvb, 1048576);
  cvt_k<<<1024, 256, 0, stream>>>(o_w, wob, 1048576);
  cvt_k<<<4096, 256, 0, stream>>>(w1, w1b, 4194304);
  cvt_k<<<4096, 256, 0, stream>>>(w2, w2b, 4194304);
  cvt_k<<<4096, 256, 0, stream>>>(w3, w3b, 4194304);

  rmsnorm_k<<<4096, 256, 0, stream>>>(in_f, ln1, xn);

  dim3 g8(32, 8), g32(32, 32);
  gemm_bt<1><<<g8, 256, 0, stream>>>(xn, wqb, 1024, 1024, qb, nullptr, nullptr, nullptr);
  gemm_bt<1><<<g8, 256, 0, stream>>>(xn, wkb, 1024, 1024, kb, nullptr, nullptr, nullptr);
  gemm_bt<1><<<g8, 256, 0, stream>>>(xn, wvb, 1024, 1024, vb, nullptr, nullptr, nullptr);

  rope_k<<<8192, 256, 0, stream>>>(qb, pos);
  rope_k<<<8192, 256, 0, stream>>>(kb, pos);

  attn_k<<<dim3(32, 32), 256, 0, stream>>>(qb, kb, vb, cx);

  gemm_bt<2><<<g8, 256, 0, stream>>>(cx, wob, 1024, 1024, nullptr, out, in_f, nullptr);

  rmsnorm_k<<<4096, 256, 0, stream>>>(out, ln2, xn);

  gemm_bt<0><<<g32, 256, 0, stream>>>(xn, w1b, 1024, 4096, gb, nullptr, nullptr, nullptr);
  gemm_bt<3><<<g32, 256, 0, stream>>>(xn, w3b, 1024, 4096, hb, nullptr, nullptr, gb);

  gemm_bt<2><<<g8, 256, 0, stream>>>(hb, w2b, 4096, 1024, nullptr, out, out, nullptr);
}

// Round 2
// 400.910 us; speedup vs baseline: 1.2889x; 1.2889x over previous
//
#include <hip/hip_runtime.h>
#include <hip/hip_bf16.h>

typedef __attribute__((ext_vector_type(8))) __bf16 bf16x8;
typedef __attribute__((ext_vector_type(4))) float f32x4;

#define DEV static __device__ __forceinline__

DEV unsigned short f2bf(float f) {
  union { float f; unsigned int u; } v; v.f = f;
  unsigned int u = v.u;
  unsigned int r = (u + 0x7fffu + ((u >> 16) & 1u)) >> 16;
  return (unsigned short)r;
}
DEV float bf2f(unsigned short h) {
  union { unsigned int u; float f; } v; v.u = ((unsigned int)h) << 16;
  return v.f;
}
DEV f32x4 mfma16(bf16x8 a, bf16x8 b, f32x4 c) {
  return __builtin_amdgcn_mfma_f32_16x16x32_bf16(a, b, c, 0, 0, 0);
}
DEV void gload_lds16(const void* g, void* l) {
  __builtin_amdgcn_global_load_lds((__attribute__((address_space(1))) void*)g,
                                   (__attribute__((address_space(3))) void*)l,
                                   16, 0, 0);
}

// ---------------- f32 -> bf16 convert ----------------
__global__ __launch_bounds__(256) void cvt_k(const float* __restrict__ in,
                                             unsigned short* __restrict__ out, int n) {
  int i = (blockIdx.x * 256 + threadIdx.x) * 4;
  if (i + 3 < n) {
    float4 v = *(const float4*)(in + i);
    out[i + 0] = f2bf(v.x);
    out[i + 1] = f2bf(v.y);
    out[i + 2] = f2bf(v.z);
    out[i + 3] = f2bf(v.w);
  }
}

// ---------------- RMSNorm: fp32 in -> bf16 out (D=1024) ----------------
__global__ __launch_bounds__(256) void rmsnorm_k(const float* __restrict__ x,
                                                 const float* __restrict__ w,
                                                 unsigned short* __restrict__ out) {
  int row = blockIdx.x;
  int tid = threadIdx.x;
  const float* xr = x + (size_t)row * 1024;
  float4 v = *(const float4*)(xr + tid * 4);
  float ss = v.x * v.x + v.y * v.y + v.z * v.z + v.w * v.w;
#pragma unroll
  for (int m = 32; m >= 1; m >>= 1) ss += __shfl_xor(ss, m);
  __shared__ float red[4];
  int wid = tid >> 6;
  if ((tid & 63) == 0) red[wid] = ss;
  __syncthreads();
  float tot = red[0] + red[1] + red[2] + red[3];
  float rs = rsqrtf(tot * (1.0f / 1024.0f) + 1e-5f);
  float4 wv = *(const float4*)(w + tid * 4);
  unsigned short* o = out + (size_t)row * 1024 + tid * 4;
  o[0] = f2bf(v.x * rs * wv.x);
  o[1] = f2bf(v.y * rs * wv.y);
  o[2] = f2bf(v.z * rs * wv.z);
  o[3] = f2bf(v.w * rs * wv.w);
}

// ---------------- RoPE in-place on [BH=32][S=2048][64] bf16 ----------------
__global__ __launch_bounds__(256) void rope_k(unsigned short* __restrict__ x,
                                              const int* __restrict__ pos) {
  int idx = blockIdx.x * 256 + threadIdx.x;  // B*H*S*32 = 2,097,152 threads
  int i = idx & 31;
  int s = (idx >> 5) & 2047;
  int bh = idx >> 16;
  int b = bh >> 4;
  float p = (float)pos[b * 2048 + s];
  float inv = exp2f(-(float)i * 0.4152410118609203f);
  float ang = p * inv;
  float sn = sinf(ang), cs = cosf(ang);
  size_t base = (((size_t)bh * 2048) + s) * 64 + 2 * i;
  float x1 = bf2f(x[base]), x2 = bf2f(x[base + 1]);
  x[base]     = f2bf(x1 * cs - x2 * sn);
  x[base + 1] = f2bf(x1 * sn + x2 * cs);
}

// ---------------- GEMM: C[M,N] = A[M,K](bf16) * Bw[N,K]^T(bf16) ----------------
// MODE 0: store bf16 C[m*N+n]
// MODE 1: QKV scatter bf16 -> [b][h][s][d]  (m=b*2048+s, n=h*64+d)
// MODE 2: outf[m*N+n] = resid[m*N+n] + acc   (fp32)
// MODE 3: outb[m*N+n] = silu(gate[m*N+n]) * acc  (bf16)
// MODE 4: V^T scatter: A=Wv rows (m=e=h*64+dd), B=xn rows (n=b*2048+s)
//         -> outb[((b*16+h)*64+dd)*2048 + s]
template <int MODE>
__global__ __launch_bounds__(256) void gemm_bt(const unsigned short* __restrict__ A,
                                               const unsigned short* __restrict__ Bw,
                                               int K, int N,
                                               unsigned short* __restrict__ outb,
                                               float* __restrict__ outf,
                                               const float* __restrict__ resid,
                                               const unsigned short* __restrict__ gate) {
  __shared__ __align__(16) unsigned short As[128 * 64];
  __shared__ __align__(16) unsigned short Bs[128 * 64];
  const int tid = threadIdx.x;
  const int wid = tid >> 6, lane = tid & 63;
  const int wr = wid >> 1, wc = wid & 1;
  const int m0 = blockIdx.x * 128, n0 = blockIdx.y * 128;
  const int sw = (lane & 7) * 8;   // read-side XOR swizzle (u16 units)
  f32x4 acc[4][4] = {};

  for (int k0 = 0; k0 < K; k0 += 64) {
    __syncthreads();  // previous-iter LDS reads done before overwrite
#pragma unroll
    for (int it = 0; it < 4; ++it) {
      int c = wid * 4 + it;              // 16 chunks of 1024B
      int row = c * 8 + (lane >> 3);
      int col = ((lane & 7) ^ (row & 7)) * 8;   // inverse-swizzled source
      gload_lds16(A + (size_t)(m0 + row) * K + k0 + col, As + c * 512);
      gload_lds16(Bw + (size_t)(n0 + row) * K + k0 + col, Bs + c * 512);
    }
    asm volatile("s_waitcnt vmcnt(0)" ::: "memory");
    __syncthreads();
#pragma unroll
    for (int kk = 0; kk < 2; ++kk) {
      const int kof = (kk * 32 + (lane >> 4) * 8) ^ sw;
      bf16x8 af[4], bfr[4];
#pragma unroll
      for (int i = 0; i < 4; ++i) {
        af[i]  = *(const bf16x8*)(As + (wr * 64 + i * 16 + (lane & 15)) * 64 + kof);
        bfr[i] = *(const bf16x8*)(Bs + (wc * 64 + i * 16 + (lane & 15)) * 64 + kof);
      }
#pragma unroll
      for (int i = 0; i < 4; ++i)
#pragma unroll
        for (int j = 0; j < 4; ++j) acc[i][j] = mfma16(af[i], bfr[j], acc[i][j]);
    }
  }

  const int rb = m0 + wr * 64 + ((lane >> 4) * 4);
  const int cb = n0 + wc * 64 + (lane & 15);
#pragma unroll
  for (int i = 0; i < 4; ++i) {
#pragma unroll
    for (int r = 0; r < 4; ++r) {
      int m = rb + i * 16 + r;
#pragma unroll
      for (int j = 0; j < 4; ++j) {
        int n = cb + j * 16;
        float val = acc[i][j][r];
        if (MODE == 0) {
          outb[(size_t)m * N + n] = f2bf(val);
        } else if (MODE == 1) {
          int b = m >> 11, s = m & 2047, hh = n >> 6, dd = n & 63;
          outb[(((size_t)b * 16 + hh) * 2048 + s) * 64 + dd] = f2bf(val);
        } else if (MODE == 2) {
          size_t idx = (size_t)m * N + n;
          outf[idx] = resid[idx] + val;
        } else if (MODE == 3) {
          size_t idx = (size_t)m * N + n;
          float gv = bf2f(gate[idx]);
          float sg = gv / (1.0f + __expf(-gv));
          outb[idx] = f2bf(sg * val);
        } else {  // MODE 4
          int bb = n >> 11, s = n & 2047, hh = m >> 6, dd = m & 63;
          outb[(((size_t)bb * 16 + hh) * 64 + dd) * 2048 + s] = f2bf(val);
        }
      }
    }
  }
}

// ---------------- Flash attention ----------------
// q,k: [BH][S][64] bf16 (RoPE'd);  vt: [BH][64][S] bf16 (pre-transposed)
// ctx: [B][S][1024] bf16
// Triangle pairing: block p handles q-tiles p and 31-p (33 KV-iters each).
__global__ __launch_bounds__(256) void attn_k(const unsigned short* __restrict__ q,
                                              const unsigned short* __restrict__ k,
                                              const unsigned short* __restrict__ vt,
                                              unsigned short* __restrict__ ctx) {
  __shared__ __align__(16) unsigned short Ks[64 * 64];
  __shared__ __align__(16) unsigned short Vs[64 * 64];   // [d][kv], swizzled
  __shared__ __align__(16) unsigned short Ps[4][16 * 72];
  const int p = blockIdx.x, bh = blockIdx.y;
  const int tid = threadIdx.x, wid = tid >> 6, lane = tid & 63;
  const size_t bhS = (size_t)bh * 2048;
  const size_t bhD = (size_t)bh * 64 * 2048;
  const int b = bh >> 4, hh = bh & 15;
  const int sw = (lane & 7) * 8;

  for (int half = 0; half < 2; ++half) {
    const int qt = half ? (31 - p) : p;
    const int q0 = qt * 64;

    bf16x8 qf[2];
    {
      const unsigned short* qp = q + (bhS + q0 + wid * 16 + (lane & 15)) * 64 + (lane >> 4) * 8;
      qf[0] = *(const bf16x8*)qp;
      qf[1] = *(const bf16x8*)(qp + 32);
    }
    float mrow[4], lrow[4];
    f32x4 o[4] = {};
#pragma unroll
    for (int r = 0; r < 4; ++r) { mrow[r] = -1e30f; lrow[r] = 0.0f; }
    const int rowb = q0 + wid * 16 + ((lane >> 4) * 4);

    for (int kt = 0; kt <= qt; ++kt) {
      __syncthreads();
#pragma unroll
      for (int it = 0; it < 2; ++it) {
        int c = wid * 2 + it;  // 8 chunks of 1024B
        int row = c * 8 + (lane >> 3);
        int col = ((lane & 7) ^ (row & 7)) * 8;
        gload_lds16(k + (bhS + kt * 64 + row) * 64 + col, Ks + c * 512);
        gload_lds16(vt + bhD + (size_t)row * 2048 + kt * 64 + col, Vs + c * 512);
      }
      asm volatile("s_waitcnt vmcnt(0)" ::: "memory");
      __syncthreads();

      // S = Q K^T  (16 q-rows x 64 keys per wave)
      f32x4 s[4];
#pragma unroll
      for (int nt = 0; nt < 4; ++nt) {
        f32x4 z = {};
#pragma unroll
        for (int ks = 0; ks < 2; ++ks) {
          int kof = (ks * 32 + (lane >> 4) * 8) ^ sw;
          bf16x8 kf = *(const bf16x8*)(Ks + (nt * 16 + (lane & 15)) * 64 + kof);
          z = mfma16(qf[ks], kf, z);
        }
        s[nt] = z;
      }
      const bool diag = (kt == qt);
#pragma unroll
      for (int r = 0; r < 4; ++r) {
        float mx = -1e30f;
#pragma unroll
        for (int nt = 0; nt < 4; ++nt) {
          float val = s[nt][r] * 0.125f;
          if (diag && (kt * 64 + nt * 16 + (lane & 15)) > (rowb + r)) val = -1e30f;
          s[nt][r] = val;
          mx = fmaxf(mx, val);
        }
        mx = fmaxf(mx, __shfl_xor(mx, 1));
        mx = fmaxf(mx, __shfl_xor(mx, 2));
        mx = fmaxf(mx, __shfl_xor(mx, 4));
        mx = fmaxf(mx, __shfl_xor(mx, 8));
        float mnew = fmaxf(mrow[r], mx);
        float sum = 0.0f;
#pragma unroll
        for (int nt = 0; nt < 4; ++nt) {
          float pv = __expf(s[nt][r] - mnew);
          s[nt][r] = pv;
          sum += pv;
        }
        sum += __shfl_xor(sum, 1);
        sum += __shfl_xor(sum, 2);
        sum += __shfl_xor(sum, 4);
        sum += __shfl_xor(sum, 8);
        float alpha = __expf(mrow[r] - mnew);
        lrow[r] = lrow[r] * alpha + sum;
        mrow[r] = mnew;
#pragma unroll
        for (int d = 0; d < 4; ++d) o[d][r] *= alpha;
      }
      // P -> LDS (per-wave private, padded stride 72), then PV
#pragma unroll
      for (int nt = 0; nt < 4; ++nt)
#pragma unroll
        for (int r = 0; r < 4; ++r)
          Ps[wid][((lane >> 4) * 4 + r) * 72 + nt * 16 + (lane & 15)] = f2bf(s[nt][r]);
      __syncthreads();
#pragma unroll
      for (int ks = 0; ks < 2; ++ks) {
        bf16x8 pf = *(const bf16x8*)(&Ps[wid][(lane & 15) * 72 + ks * 32 + (lane >> 4) * 8]);
        int kof = (ks * 32 + (lane >> 4) * 8) ^ sw;
#pragma unroll
        for (int d = 0; d < 4; ++d) {
          bf16x8 vf = *(const bf16x8*)(Vs + (d * 16 + (lane & 15)) * 64 + kof);
          o[d] = mfma16(pf, vf, o[d]);
        }
      }
    }
#pragma unroll
    for (int d = 0; d < 4; ++d)
#pragma unroll
      for (int r = 0; r < 4; ++r) {
        float val = o[d][r] / lrow[r];
        ctx[((size_t)b * 2048 + (rowb + r)) * 1024 + hh * 64 + d * 16 + (lane & 15)] = f2bf(val);
      }
  }
}

extern "C" void kernel_launch(void* const* d_in, const int* in_sizes, int n_in,
                              void* d_out, int out_size, void* d_ws, size_t ws_size,
                              hipStream_t stream) {
  (void)in_sizes; (void)n_in; (void)out_size; (void)ws_size;
  const float* in_f = (const float*)d_in[0];
  const int* pos    = (const int*)d_in[1];
  const float* q_w  = (const float*)d_in[2];
  const float* k_w  = (const float*)d_in[3];
  const float* v_w  = (const float*)d_in[4];
  const float* o_w  = (const float*)d_in[5];
  const float* ln1  = (const float*)d_in[6];
  const float* ln2  = (const float*)d_in[7];
  const float* w1   = (const float*)d_in[8];
  const float* w2   = (const float*)d_in[9];
  const float* w3   = (const float*)d_in[10];
  float* out = (float*)d_out;

  unsigned short* ws = (unsigned short*)d_ws;
  size_t off = 0;
  auto alloc = [&](size_t n) { unsigned short* p = ws + off; off += n; return p; };
  unsigned short* wqb = alloc(1048576);
  unsigned short* wkb = alloc(1048576);
  unsigned short* wvb = alloc(1048576);
  unsigned short* wob = alloc(1048576);
  unsigned short* w1b = alloc(4194304);
  unsigned short* w2b = alloc(4194304);
  unsigned short* w3b = alloc(4194304);
  unsigned short* xn  = alloc(4194304);   // reused for xn2
  unsigned short* qb  = alloc(4194304);
  unsigned short* kb  = alloc(4194304);
  unsigned short* vb  = alloc(4194304);   // V^T: [bh][64][2048]
  unsigned short* cx  = alloc(4194304);
  unsigned short* gb  = alloc(16777216);
  unsigned short* hb  = alloc(16777216);

  cvt_k<<<1024, 256, 0, stream>>>(q_w, wqb, 1048576);
  cvt_k<<<1024, 256, 0, stream>>>(k_w, wkb, 1048576);
  cvt_k<<<1024, 256, 0, stream>>>(v_w, wvb, 1048576);
  cvt_k<<<1024, 256, 0, stream>>>(o_w, wob, 1048576);
  cvt_k<<<4096, 256, 0, stream>>>(w1, w1b, 4194304);
  cvt_k<<<4096, 256, 0, stream>>>(w2, w2b, 4194304);
  cvt_k<<<4096, 256, 0, stream>>>(w3, w3b, 4194304);

  rmsnorm_k<<<4096, 256, 0, stream>>>(in_f, ln1, xn);

  dim3 g8(32, 8), g32(32, 32);
  gemm_bt<1><<<g8, 256, 0, stream>>>(xn, wqb, 1024, 1024, qb, nullptr, nullptr, nullptr);
  gemm_bt<1><<<g8, 256, 0, stream>>>(xn, wkb, 1024, 1024, kb, nullptr, nullptr, nullptr);
  gemm_bt<4><<<dim3(8, 32), 256, 0, stream>>>(wvb, xn, 1024, 4096, vb, nullptr, nullptr, nullptr);

  rope_k<<<8192, 256, 0, stream>>>(qb, pos);
  rope_k<<<8192, 256, 0, stream>>>(kb, pos);

  attn_k<<<dim3(16, 32), 256, 0, stream>>>(qb, kb, vb, cx);

  gemm_bt<2><<<g8, 256, 0, stream>>>(cx, wob, 1024, 1024, nullptr, out, in_f, nullptr);

  rmsnorm_k<<<4096, 256, 0, stream>>>(out, ln2, xn);

  gemm_bt<0><<<g32, 256, 0, stream>>>(xn, w1b, 1024, 4096, gb, nullptr, nullptr, nullptr);
  gemm_bt<3><<<g32, 256, 0, stream>>>(xn, w3b, 1024, 4096, hb, nullptr, nullptr, gb);

  gemm_bt<2><<<g8, 256, 0, stream>>>(hb, w2b, 4096, 1024, nullptr, out, out, nullptr);
}

// Round 3
// 335.260 us; speedup vs baseline: 1.5413x; 1.1958x over previous
//
#include <hip/hip_runtime.h>
#include <hip/hip_bf16.h>

typedef __attribute__((ext_vector_type(8))) __bf16 bf16x8;
typedef __attribute__((ext_vector_type(4))) float f32x4;

#define DEV static __device__ __forceinline__

DEV unsigned short f2bf(float f) {
  union { float f; unsigned int u; } v; v.f = f;
  unsigned int u = v.u;
  unsigned int r = (u + 0x7fffu + ((u >> 16) & 1u)) >> 16;
  return (unsigned short)r;
}
DEV float bf2f(unsigned short h) {
  union { unsigned int u; float f; } v; v.u = ((unsigned int)h) << 16;
  return v.f;
}
DEV f32x4 mfma16(bf16x8 a, bf16x8 b, f32x4 c) {
  return __builtin_amdgcn_mfma_f32_16x16x32_bf16(a, b, c, 0, 0, 0);
}
DEV void gload_lds16(const void* g, void* l) {
  __builtin_amdgcn_global_load_lds((__attribute__((address_space(1))) void*)g,
                                   (__attribute__((address_space(3))) void*)l,
                                   16, 0, 0);
}

// ---------------- fused f32 -> bf16 convert of all 7 weights ----------------
struct CvtArgs { const float* src[7]; int cum[8]; };
__global__ __launch_bounds__(256) void cvt_all(CvtArgs a, unsigned short* __restrict__ dst) {
  int i = (blockIdx.x * 256 + threadIdx.x) * 4;
  if (i >= a.cum[7]) return;
  int w = 0;
#pragma unroll 7
  for (int t = 0; t < 7; ++t) if (i >= a.cum[t + 1]) w = t + 1;
  float4 v = *(const float4*)(a.src[w] + (i - a.cum[w]));
  dst[i + 0] = f2bf(v.x);
  dst[i + 1] = f2bf(v.y);
  dst[i + 2] = f2bf(v.z);
  dst[i + 3] = f2bf(v.w);
}

// ---------------- RMSNorm: fp32 in -> bf16 out (D=1024) ----------------
__global__ __launch_bounds__(256) void rmsnorm_k(const float* __restrict__ x,
                                                 const float* __restrict__ w,
                                                 unsigned short* __restrict__ out) {
  int row = blockIdx.x;
  int tid = threadIdx.x;
  const float* xr = x + (size_t)row * 1024;
  float4 v = *(const float4*)(xr + tid * 4);
  float ss = v.x * v.x + v.y * v.y + v.z * v.z + v.w * v.w;
#pragma unroll
  for (int m = 32; m >= 1; m >>= 1) ss += __shfl_xor(ss, m);
  __shared__ float red[4];
  int wid = tid >> 6;
  if ((tid & 63) == 0) red[wid] = ss;
  __syncthreads();
  float tot = red[0] + red[1] + red[2] + red[3];
  float rs = rsqrtf(tot * (1.0f / 1024.0f) + 1e-5f);
  float4 wv = *(const float4*)(w + tid * 4);
  unsigned short* o = out + (size_t)row * 1024 + tid * 4;
  o[0] = f2bf(v.x * rs * wv.x);
  o[1] = f2bf(v.y * rs * wv.y);
  o[2] = f2bf(v.z * rs * wv.z);
  o[3] = f2bf(v.w * rs * wv.w);
}

// ---------------- RoPE in-place on q and k, [BH=32][S=2048][64] bf16 ----------------
__global__ __launch_bounds__(256) void rope2_k(unsigned short* __restrict__ q,
                                               unsigned short* __restrict__ k,
                                               const int* __restrict__ pos) {
  int gid = blockIdx.x * 256 + threadIdx.x;  // 2 * 2,097,152
  unsigned short* x = (gid < 2097152) ? q : k;
  int idx = gid & 2097151;
  int i = idx & 31;
  int s = (idx >> 5) & 2047;
  int bh = idx >> 16;
  int b = bh >> 4;
  float p = (float)pos[b * 2048 + s];
  float inv = exp2f(-(float)i * 0.4152410118609203f);
  float ang = p * inv;
  float sn = sinf(ang), cs = cosf(ang);
  size_t base = (((size_t)bh * 2048) + s) * 64 + 2 * i;
  float x1 = bf2f(x[base]), x2 = bf2f(x[base + 1]);
  x[base]     = f2bf(x1 * cs - x2 * sn);
  x[base + 1] = f2bf(x1 * sn + x2 * cs);
}

// ================= 256x256 8-phase GEMM: C[M,N] = A[M,K] * B[N,K]^T =================
// MODE 0: QK scatter (n<1024 -> q, else k): [b][h][s][d]
// MODE 1: V^T scatter: m=e(h*64+dd), n=token -> [((b*16+h)*64+dd)*2048 + s]
// MODE 2: outf[m*1024+n] = resid + acc (fp32)
// MODE 3: outb[m*4096+n] = bf16(acc)
// MODE 4: outb[m*4096+n] = silu(gate)*acc (bf16)
// MODE 5: outf[m*1024+n] = acc (fp32 partial, outf pre-offset by z)
template <int MODE>
DEV void gemm8_body(const unsigned short* __restrict__ A, int lda,
                    const unsigned short* __restrict__ B, int ldb,
                    int bm, int bn, int kbase, int nt,
                    unsigned short* __restrict__ outb, float* __restrict__ outf,
                    const float* __restrict__ resid, const unsigned short* __restrict__ gate,
                    unsigned short* As, unsigned short* Bs) {
  const int tid = threadIdx.x;
  const int lane = tid & 63, wid = tid >> 6;
  const int wr = wid >> 2, wc = wid & 3;
  const int m0 = bm * 256, n0 = bn * 256;

  // staging geometry: 1024 units of 8 u16 per half-tile slot; unit u: row=u>>2, slot c=u&3
  const int r0 = tid >> 2, r1 = 128 + (tid >> 2), cc = tid & 3;
  const int sc0 = (cc ^ ((r0 >> 1) & 3)) * 8;   // source k-offset permutation
  const int sc1 = (cc ^ ((r1 >> 1) & 3)) * 8;
  const size_t arow0 = (size_t)(m0 + r0) * lda, arow1 = (size_t)(m0 + r1) * lda;
  const size_t brow0 = (size_t)(n0 + r0) * ldb, brow1 = (size_t)(n0 + r1) * ldb;
  const int du0 = tid * 8, du1 = (512 + tid) * 8;

  auto stA = [&](int t, int kh) {
    unsigned short* d = As + ((((t & 1) << 1) | kh) * 8192);
    const unsigned short* s = A + kbase + t * 64 + kh * 32;
    gload_lds16(s + arow0 + sc0, d + du0);
    gload_lds16(s + arow1 + sc1, d + du1);
  };
  auto stB = [&](int t, int kh) {
    unsigned short* d = Bs + ((((t & 1) << 1) | kh) * 8192);
    const unsigned short* s = B + kbase + t * 64 + kh * 32;
    gload_lds16(s + brow0 + sc0, d + du0);
    gload_lds16(s + brow1 + sc1, d + du1);
  };

  // fragment read addressing (swizzled)
  const int fcol = ((lane >> 4) ^ ((lane >> 1) & 3)) * 8;
  const int frow = lane & 15;
  const int abase = (wr * 128 + frow) * 32 + fcol;  // + mh*2048 + fi*512
  const int bbase = (wc * 64 + frow) * 32 + fcol;   // + j*512

  f32x4 acc[8][4] = {};
  bf16x8 a[4], b[4];

#define LOADA(buf, ks, mh) { const unsigned short* p_ = As + (((buf) << 1) | (ks)) * 8192 + abase + (mh) * 2048; \
  a[0] = *(const bf16x8*)(p_); a[1] = *(const bf16x8*)(p_ + 512); \
  a[2] = *(const bf16x8*)(p_ + 1024); a[3] = *(const bf16x8*)(p_ + 1536); }
#define LOADB(buf, ks) { const unsigned short* p_ = Bs + (((buf) << 1) | (ks)) * 8192 + bbase; \
  b[0] = *(const bf16x8*)(p_); b[1] = *(const bf16x8*)(p_ + 512); \
  b[2] = *(const bf16x8*)(p_ + 1024); b[3] = *(const bf16x8*)(p_ + 1536); }
#define MFMAQ(mh) { _Pragma("unroll") for (int fi = 0; fi < 4; ++fi) \
  _Pragma("unroll") for (int j = 0; j < 4; ++j) \
    acc[(mh) * 4 + fi][j] = mfma16(a[fi], b[j], acc[(mh) * 4 + fi][j]); }
#define LGK0() { asm volatile("s_waitcnt lgkmcnt(0)" ::: "memory"); __builtin_amdgcn_sched_barrier(0); }

  // prologue: Ka(0), Kb(0), Ka(1)  (nt >= 2 always)
  stA(0, 0); stB(0, 0); stA(0, 1); stB(0, 1);
  stA(1, 0); stB(1, 0);
  asm volatile("s_waitcnt vmcnt(4)" ::: "memory");
  __builtin_amdgcn_s_barrier();

  for (int t = 0; t < nt; ++t) {
    const int buf = t & 1;
    // phase 0: ks=0 mh=0 (A+B), stage A-Kb(t+1)
    LOADA(buf, 0, 0); LOADB(buf, 0);
    if (t + 1 < nt) stA(t + 1, 1);
    __builtin_amdgcn_s_barrier();
    LGK0();
    __builtin_amdgcn_s_setprio(1); MFMAQ(0); __builtin_amdgcn_s_setprio(0);
    __builtin_amdgcn_s_barrier();
    // phase 1: ks=0 mh=1 (A), stage B-Kb(t+1)
    LOADA(buf, 0, 1);
    if (t + 1 < nt) stB(t + 1, 1);
    __builtin_amdgcn_s_barrier();
    LGK0();
    __builtin_amdgcn_s_setprio(1); MFMAQ(1); __builtin_amdgcn_s_setprio(0);
    __builtin_amdgcn_s_barrier();
    // phase 2: ks=1 mh=0 (A+B), stage A-Ka(t+2)
    LOADA(buf, 1, 0); LOADB(buf, 1);
    if (t + 2 < nt) stA(t + 2, 0);
    __builtin_amdgcn_s_barrier();
    LGK0();
    __builtin_amdgcn_s_setprio(1); MFMAQ(0); __builtin_amdgcn_s_setprio(0);
    __builtin_amdgcn_s_barrier();
    // phase 3: ks=1 mh=1 (A), stage B-Ka(t+2)
    LOADA(buf, 1, 1);
    if (t + 2 < nt) stB(t + 2, 0);
    __builtin_amdgcn_s_barrier();
    LGK0();
    __builtin_amdgcn_s_setprio(1); MFMAQ(1); __builtin_amdgcn_s_setprio(0);
    // tile boundary: counted vmcnt, never 0 until the last
    if (t + 1 < nt) {
      if (t + 2 < nt) { asm volatile("s_waitcnt vmcnt(4)" ::: "memory"); }
      else            { asm volatile("s_waitcnt vmcnt(0)" ::: "memory"); }
      __builtin_amdgcn_s_barrier();
    }
  }
#undef LOADA
#undef LOADB
#undef MFMAQ
#undef LGK0

  // epilogue
#pragma unroll
  for (int i = 0; i < 8; ++i)
#pragma unroll
    for (int j = 0; j < 4; ++j)
#pragma unroll
      for (int r = 0; r < 4; ++r) {
        int m = m0 + wr * 128 + i * 16 + ((lane >> 4) << 2) + r;
        int n = n0 + wc * 64 + j * 16 + (lane & 15);
        float v = acc[i][j][r];
        if (MODE == 0) {
          unsigned short* dst = outb + ((n >= 1024) ? 4194304 : 0);
          int nn = n & 1023;
          int bb = m >> 11, s = m & 2047, hh = nn >> 6, dd = nn & 63;
          dst[(((size_t)bb * 16 + hh) * 2048 + s) * 64 + dd] = f2bf(v);
        } else if (MODE == 1) {
          int hh = m >> 6, dd = m & 63, bb = n >> 11, s = n & 2047;
          outb[(((size_t)bb * 16 + hh) * 64 + dd) * 2048 + s] = f2bf(v);
        } else if (MODE == 2) {
          size_t idx = (size_t)m * 1024 + n;
          outf[idx] = resid[idx] + v;
        } else if (MODE == 3) {
          outb[(size_t)m * 4096 + n] = f2bf(v);
        } else if (MODE == 4) {
          size_t idx = (size_t)m * 4096 + n;
          float g = bf2f(gate[idx]);
          outb[idx] = f2bf(g / (1.0f + __expf(-g)) * v);
        } else {
          outf[(size_t)m * 1024 + n] = v;
        }
      }
}

DEV void swz_map(int bid, int nwg, int MT, int& bm, int& bn) {
  int cpx = nwg >> 3;
  int sw = (bid & 7) * cpx + (bid >> 3);
  bm = sw % MT;
  bn = sw / MT;
}

template <int MODE>
__global__ __launch_bounds__(512, 2) void gemm8_k(const unsigned short* __restrict__ A, int lda,
                                                  const unsigned short* __restrict__ B, int ldb,
                                                  int MT, int kz, int nt,
                                                  unsigned short* __restrict__ outb,
                                                  float* __restrict__ outf,
                                                  const float* __restrict__ resid,
                                                  const unsigned short* __restrict__ gate) {
  __shared__ __align__(16) unsigned short lds[65536];
  int bm, bn;
  swz_map(blockIdx.x, gridDim.x, MT, bm, bn);
  int kb = kz * blockIdx.y;
  float* of = outf;
  if (MODE == 5) of += (size_t)blockIdx.y * 4194304;
  gemm8_body<MODE>(A, lda, B, ldb, bm, bn, kb, nt, outb, of, resid, gate, lds, lds + 32768);
}

// combined QK-projection + V^T-projection launch (192 blocks)
__global__ __launch_bounds__(512, 2) void gemm8_qkv(const unsigned short* __restrict__ xn,
                                                    const unsigned short* __restrict__ wqk,
                                                    const unsigned short* __restrict__ wv,
                                                    unsigned short* __restrict__ qk_out,
                                                    unsigned short* __restrict__ vt_out) {
  __shared__ __align__(16) unsigned short lds[65536];
  int bid = blockIdx.x;
  if (bid < 128) {
    int bm, bn;
    swz_map(bid, 128, 16, bm, bn);
    gemm8_body<0>(xn, 1024, wqk, 1024, bm, bn, 0, 16, qk_out, nullptr, nullptr, nullptr, lds, lds + 32768);
  } else {
    bid -= 128;
    int bm, bn;
    swz_map(bid, 64, 4, bm, bn);
    gemm8_body<1>(wv, 1024, xn, 1024, bm, bn, 0, 16, vt_out, nullptr, nullptr, nullptr, lds, lds + 32768);
  }
}

// ---------------- w2 split-K reduce: out += sum of 4 partials ----------------
__global__ __launch_bounds__(256) void reduce_k(float* __restrict__ out,
                                                const float* __restrict__ part) {
  int i = (blockIdx.x * 256 + threadIdx.x) * 4;
  float4 o = *(const float4*)(out + i);
  float4 p0 = *(const float4*)(part + i);
  float4 p1 = *(const float4*)(part + 4194304 + i);
  float4 p2 = *(const float4*)(part + 8388608 + i);
  float4 p3 = *(const float4*)(part + 12582912 + i);
  o.x += p0.x + p1.x + p2.x + p3.x;
  o.y += p0.y + p1.y + p2.y + p3.y;
  o.z += p0.z + p1.z + p2.z + p3.z;
  o.w += p0.w + p1.w + p2.w + p3.w;
  *(float4*)(out + i) = o;
}

// ---------------- Flash attention (round-1, swizzled) ----------------
__global__ __launch_bounds__(256) void attn_k(const unsigned short* __restrict__ q,
                                              const unsigned short* __restrict__ k,
                                              const unsigned short* __restrict__ vt,
                                              unsigned short* __restrict__ ctx) {
  __shared__ __align__(16) unsigned short Ks[64 * 64];
  __shared__ __align__(16) unsigned short Vs[64 * 64];
  __shared__ __align__(16) unsigned short Ps[4][16 * 72];
  const int p = blockIdx.x, bh = blockIdx.y;
  const int tid = threadIdx.x, wid = tid >> 6, lane = tid & 63;
  const size_t bhS = (size_t)bh * 2048;
  const size_t bhD = (size_t)bh * 64 * 2048;
  const int b = bh >> 4, hh = bh & 15;
  const int sw = (lane & 7) * 8;

  for (int half = 0; half < 2; ++half) {
    const int qt = half ? (31 - p) : p;
    const int q0 = qt * 64;

    bf16x8 qf[2];
    {
      const unsigned short* qp = q + (bhS + q0 + wid * 16 + (lane & 15)) * 64 + (lane >> 4) * 8;
      qf[0] = *(const bf16x8*)qp;
      qf[1] = *(const bf16x8*)(qp + 32);
    }
    float mrow[4], lrow[4];
    f32x4 o[4] = {};
#pragma unroll
    for (int r = 0; r < 4; ++r) { mrow[r] = -1e30f; lrow[r] = 0.0f; }
    const int rowb = q0 + wid * 16 + ((lane >> 4) * 4);

    for (int kt = 0; kt <= qt; ++kt) {
      __syncthreads();
#pragma unroll
      for (int it = 0; it < 2; ++it) {
        int c = wid * 2 + it;
        int row = c * 8 + (lane >> 3);
        int col = ((lane & 7) ^ (row & 7)) * 8;
        gload_lds16(k + (bhS + kt * 64 + row) * 64 + col, Ks + c * 512);
        gload_lds16(vt + bhD + (size_t)row * 2048 + kt * 64 + col, Vs + c * 512);
      }
      asm volatile("s_waitcnt vmcnt(0)" ::: "memory");
      __syncthreads();

      f32x4 s[4];
#pragma unroll
      for (int nt = 0; nt < 4; ++nt) {
        f32x4 z = {};
#pragma unroll
        for (int ks = 0; ks < 2; ++ks) {
          int kof = (ks * 32 + (lane >> 4) * 8) ^ sw;
          bf16x8 kf = *(const bf16x8*)(Ks + (nt * 16 + (lane & 15)) * 64 + kof);
          z = mfma16(qf[ks], kf, z);
        }
        s[nt] = z;
      }
      const bool diag = (kt == qt);
#pragma unroll
      for (int r = 0; r < 4; ++r) {
        float mx = -1e30f;
#pragma unroll
        for (int nt = 0; nt < 4; ++nt) {
          float val = s[nt][r] * 0.125f;
          if (diag && (kt * 64 + nt * 16 + (lane & 15)) > (rowb + r)) val = -1e30f;
          s[nt][r] = val;
          mx = fmaxf(mx, val);
        }
        mx = fmaxf(mx, __shfl_xor(mx, 1));
        mx = fmaxf(mx, __shfl_xor(mx, 2));
        mx = fmaxf(mx, __shfl_xor(mx, 4));
        mx = fmaxf(mx, __shfl_xor(mx, 8));
        float mnew = fmaxf(mrow[r], mx);
        float sum = 0.0f;
#pragma unroll
        for (int nt = 0; nt < 4; ++nt) {
          float pv = __expf(s[nt][r] - mnew);
          s[nt][r] = pv;
          sum += pv;
        }
        sum += __shfl_xor(sum, 1);
        sum += __shfl_xor(sum, 2);
        sum += __shfl_xor(sum, 4);
        sum += __shfl_xor(sum, 8);
        float alpha = __expf(mrow[r] - mnew);
        lrow[r] = lrow[r] * alpha + sum;
        mrow[r] = mnew;
#pragma unroll
        for (int d = 0; d < 4; ++d) o[d][r] *= alpha;
      }
#pragma unroll
      for (int nt = 0; nt < 4; ++nt)
#pragma unroll
        for (int r = 0; r < 4; ++r)
          Ps[wid][((lane >> 4) * 4 + r) * 72 + nt * 16 + (lane & 15)] = f2bf(s[nt][r]);
      __syncthreads();
#pragma unroll
      for (int ks = 0; ks < 2; ++ks) {
        bf16x8 pf = *(const bf16x8*)(&Ps[wid][(lane & 15) * 72 + ks * 32 + (lane >> 4) * 8]);
        int kof = (ks * 32 + (lane >> 4) * 8) ^ sw;
#pragma unroll
        for (int d = 0; d < 4; ++d) {
          bf16x8 vf = *(const bf16x8*)(Vs + (d * 16 + (lane & 15)) * 64 + kof);
          o[d] = mfma16(pf, vf, o[d]);
        }
      }
    }
#pragma unroll
    for (int d = 0; d < 4; ++d)
#pragma unroll
      for (int r = 0; r < 4; ++r) {
        float val = o[d][r] / lrow[r];
        ctx[((size_t)b * 2048 + (rowb + r)) * 1024 + hh * 64 + d * 16 + (lane & 15)] = f2bf(val);
      }
  }
}

extern "C" void kernel_launch(void* const* d_in, const int* in_sizes, int n_in,
                              void* d_out, int out_size, void* d_ws, size_t ws_size,
                              hipStream_t stream) {
  (void)in_sizes; (void)n_in; (void)out_size; (void)ws_size;
  const float* in_f = (const float*)d_in[0];
  const int* pos    = (const int*)d_in[1];
  const float* q_w  = (const float*)d_in[2];
  const float* k_w  = (const float*)d_in[3];
  const float* v_w  = (const float*)d_in[4];
  const float* o_w  = (const float*)d_in[5];
  const float* ln1  = (const float*)d_in[6];
  const float* ln2  = (const float*)d_in[7];
  const float* w1   = (const float*)d_in[8];
  const float* w2   = (const float*)d_in[9];
  const float* w3   = (const float*)d_in[10];
  float* out = (float*)d_out;

  unsigned short* ws = (unsigned short*)d_ws;
  // layout (u16 units):
  unsigned short* wb   = ws;               // 16,777,216: [wqk 2M | wv 1M | wo 1M | w1 4M | w2 4M | w3 4M]
  unsigned short* wqkb = wb;
  unsigned short* wvb  = wb + 2097152;
  unsigned short* wob  = wb + 3145728;
  unsigned short* w1b  = wb + 4194304;
  unsigned short* w2b  = wb + 8388608;
  unsigned short* w3b  = wb + 12582912;
  unsigned short* xn   = ws + 16777216;    // 4,194,304
  unsigned short* qb   = ws + 20971520;    // 4,194,304 ([bh][s][64])
  unsigned short* kb   = ws + 25165824;    // 4,194,304 (must be qb+4194304)
  unsigned short* vb   = ws + 29360128;    // 4,194,304 (V^T [bh][64][2048])
  unsigned short* cx   = ws + 33554432;    // 4,194,304
  unsigned short* gb   = ws + 37748736;    // 16,777,216
  float* part          = (float*)(ws + 20971520);  // 16,777,216 f32, aliases qb..gb (dead by w2)
  unsigned short* hb   = ws + 54525952;    // 16,777,216

  CvtArgs ca;
  ca.src[0] = q_w; ca.src[1] = k_w; ca.src[2] = v_w; ca.src[3] = o_w;
  ca.src[4] = w1;  ca.src[5] = w2;  ca.src[6] = w3;
  ca.cum[0] = 0;        ca.cum[1] = 1048576;  ca.cum[2] = 2097152;  ca.cum[3] = 3145728;
  ca.cum[4] = 4194304;  ca.cum[5] = 8388608;  ca.cum[6] = 12582912; ca.cum[7] = 16777216;
  cvt_all<<<16384, 256, 0, stream>>>(ca, wb);

  rmsnorm_k<<<4096, 256, 0, stream>>>(in_f, ln1, xn);

  gemm8_qkv<<<192, 512, 0, stream>>>(xn, wqkb, wvb, qb, vb);

  rope2_k<<<16384, 256, 0, stream>>>(qb, kb, pos);

  attn_k<<<dim3(16, 32), 256, 0, stream>>>(qb, kb, vb, cx);

  gemm8_k<2><<<64, 512, 0, stream>>>(cx, 1024, wob, 1024, 16, 0, 16, nullptr, out, in_f, nullptr);

  rmsnorm_k<<<4096, 256, 0, stream>>>(out, ln2, xn);

  gemm8_k<3><<<256, 512, 0, stream>>>(xn, 1024, w1b, 1024, 16, 0, 16, gb, nullptr, nullptr, nullptr);
  gemm8_k<4><<<256, 512, 0, stream>>>(xn, 1024, w3b, 1024, 16, 0, 16, hb, nullptr, nullptr, gb);
  gemm8_k<5><<<dim3(64, 4), 512, 0, stream>>>(hb, 4096, w2b, 4096, 16, 1024, 16, nullptr, part, nullptr, nullptr);

  reduce_k<<<4096, 256, 0, stream>>>(out, part);
}

// Round 4
// 296.112 us; speedup vs baseline: 1.7451x; 1.1322x over previous
//
#include <hip/hip_runtime.h>
#include <hip/hip_bf16.h>

typedef __attribute__((ext_vector_type(8))) __bf16 bf16x8;
typedef __attribute__((ext_vector_type(4))) float f32x4;

#define DEV static __device__ __forceinline__

DEV unsigned short f2bf(float f) {
  union { float f; unsigned int u; } v; v.f = f;
  unsigned int u = v.u;
  unsigned int r = (u + 0x7fffu + ((u >> 16) & 1u)) >> 16;
  return (unsigned short)r;
}
DEV float bf2f(unsigned short h) {
  union { unsigned int u; float f; } v; v.u = ((unsigned int)h) << 16;
  return v.f;
}
DEV f32x4 mfma16(bf16x8 a, bf16x8 b, f32x4 c) {
  return __builtin_amdgcn_mfma_f32_16x16x32_bf16(a, b, c, 0, 0, 0);
}
DEV void gload_lds16(const void* g, void* l) {
  __builtin_amdgcn_global_load_lds((__attribute__((address_space(1))) void*)g,
                                   (__attribute__((address_space(3))) void*)l,
                                   16, 0, 0);
}
#if __has_builtin(__builtin_amdgcn_exp2f)
DEV float fexp2(float x) { return __builtin_amdgcn_exp2f(x); }
#else
DEV float fexp2(float x) { return exp2f(x); }
#endif

// ---------------- fused f32 -> bf16 convert of all 7 weights ----------------
struct CvtArgs { const float* src[7]; int cum[8]; };
__global__ __launch_bounds__(256) void cvt_all(CvtArgs a, unsigned short* __restrict__ dst) {
  int i = (blockIdx.x * 256 + threadIdx.x) * 4;
  if (i >= a.cum[7]) return;
  int w = 0;
#pragma unroll 7
  for (int t = 0; t < 7; ++t) if (i >= a.cum[t + 1]) w = t + 1;
  float4 v = *(const float4*)(a.src[w] + (i - a.cum[w]));
  dst[i + 0] = f2bf(v.x);
  dst[i + 1] = f2bf(v.y);
  dst[i + 2] = f2bf(v.z);
  dst[i + 3] = f2bf(v.w);
}

// ---------------- RMSNorm: fp32 in -> bf16 out (D=1024) ----------------
__global__ __launch_bounds__(256) void rmsnorm_k(const float* __restrict__ x,
                                                 const float* __restrict__ w,
                                                 unsigned short* __restrict__ out) {
  int row = blockIdx.x;
  int tid = threadIdx.x;
  const float* xr = x + (size_t)row * 1024;
  float4 v = *(const float4*)(xr + tid * 4);
  float ss = v.x * v.x + v.y * v.y + v.z * v.z + v.w * v.w;
#pragma unroll
  for (int m = 32; m >= 1; m >>= 1) ss += __shfl_xor(ss, m);
  __shared__ float red[4];
  int wid = tid >> 6;
  if ((tid & 63) == 0) red[wid] = ss;
  __syncthreads();
  float tot = red[0] + red[1] + red[2] + red[3];
  float rs = rsqrtf(tot * (1.0f / 1024.0f) + 1e-5f);
  float4 wv = *(const float4*)(w + tid * 4);
  unsigned short* o = out + (size_t)row * 1024 + tid * 4;
  o[0] = f2bf(v.x * rs * wv.x);
  o[1] = f2bf(v.y * rs * wv.y);
  o[2] = f2bf(v.z * rs * wv.z);
  o[3] = f2bf(v.w * rs * wv.w);
}

// ---------------- RoPE in-place on q and k, [BH=32][S=2048][64] bf16 ----------------
__global__ __launch_bounds__(256) void rope2_k(unsigned short* __restrict__ q,
                                               unsigned short* __restrict__ k,
                                               const int* __restrict__ pos) {
  int gid = blockIdx.x * 256 + threadIdx.x;
  unsigned short* x = (gid < 2097152) ? q : k;
  int idx = gid & 2097151;
  int i = idx & 31;
  int s = (idx >> 5) & 2047;
  int bh = idx >> 16;
  int b = bh >> 4;
  float p = (float)pos[b * 2048 + s];
  float inv = exp2f(-(float)i * 0.4152410118609203f);
  float ang = p * inv;
  float sn = sinf(ang), cs = cosf(ang);
  size_t base = (((size_t)bh * 2048) + s) * 64 + 2 * i;
  float x1 = bf2f(x[base]), x2 = bf2f(x[base + 1]);
  x[base]     = f2bf(x1 * cs - x2 * sn);
  x[base + 1] = f2bf(x1 * sn + x2 * cs);
}

// ================= 256x256 8-phase GEMM =================
template <int MODE>
DEV void gemm8_body(const unsigned short* __restrict__ A, int lda,
                    const unsigned short* __restrict__ B, int ldb,
                    int bm, int bn, int kbase, int nt,
                    unsigned short* __restrict__ outb, float* __restrict__ outf,
                    const float* __restrict__ resid, const unsigned short* __restrict__ gate,
                    unsigned short* As, unsigned short* Bs) {
  const int tid = threadIdx.x;
  const int lane = tid & 63, wid = tid >> 6;
  const int wr = wid >> 2, wc = wid & 3;
  const int m0 = bm * 256, n0 = bn * 256;

  const int r0 = tid >> 2, r1 = 128 + (tid >> 2), cc = tid & 3;
  const int sc0 = (cc ^ ((r0 >> 1) & 3)) * 8;
  const int sc1 = (cc ^ ((r1 >> 1) & 3)) * 8;
  const size_t arow0 = (size_t)(m0 + r0) * lda, arow1 = (size_t)(m0 + r1) * lda;
  const size_t brow0 = (size_t)(n0 + r0) * ldb, brow1 = (size_t)(n0 + r1) * ldb;
  const int du0 = tid * 8, du1 = (512 + tid) * 8;

  auto stA = [&](int t, int kh) {
    unsigned short* d = As + ((((t & 1) << 1) | kh) * 8192);
    const unsigned short* s = A + kbase + t * 64 + kh * 32;
    gload_lds16(s + arow0 + sc0, d + du0);
    gload_lds16(s + arow1 + sc1, d + du1);
  };
  auto stB = [&](int t, int kh) {
    unsigned short* d = Bs + ((((t & 1) << 1) | kh) * 8192);
    const unsigned short* s = B + kbase + t * 64 + kh * 32;
    gload_lds16(s + brow0 + sc0, d + du0);
    gload_lds16(s + brow1 + sc1, d + du1);
  };

  const int fcol = ((lane >> 4) ^ ((lane >> 1) & 3)) * 8;
  const int frow = lane & 15;
  const int abase = (wr * 128 + frow) * 32 + fcol;
  const int bbase = (wc * 64 + frow) * 32 + fcol;

  f32x4 acc[8][4] = {};
  bf16x8 a[4], b[4];

#define LOADA(buf, ks, mh) { const unsigned short* p_ = As + (((buf) << 1) | (ks)) * 8192 + abase + (mh) * 2048; \
  a[0] = *(const bf16x8*)(p_); a[1] = *(const bf16x8*)(p_ + 512); \
  a[2] = *(const bf16x8*)(p_ + 1024); a[3] = *(const bf16x8*)(p_ + 1536); }
#define LOADB(buf, ks) { const unsigned short* p_ = Bs + (((buf) << 1) | (ks)) * 8192 + bbase; \
  b[0] = *(const bf16x8*)(p_); b[1] = *(const bf16x8*)(p_ + 512); \
  b[2] = *(const bf16x8*)(p_ + 1024); b[3] = *(const bf16x8*)(p_ + 1536); }
#define MFMAQ(mh) { _Pragma("unroll") for (int fi = 0; fi < 4; ++fi) \
  _Pragma("unroll") for (int j = 0; j < 4; ++j) \
    acc[(mh) * 4 + fi][j] = mfma16(a[fi], b[j], acc[(mh) * 4 + fi][j]); }
#define LGK0() { asm volatile("s_waitcnt lgkmcnt(0)" ::: "memory"); __builtin_amdgcn_sched_barrier(0); }

  stA(0, 0); stB(0, 0); stA(0, 1); stB(0, 1);
  stA(1, 0); stB(1, 0);
  asm volatile("s_waitcnt vmcnt(4)" ::: "memory");
  __builtin_amdgcn_s_barrier();

  for (int t = 0; t < nt; ++t) {
    const int buf = t & 1;
    LOADA(buf, 0, 0); LOADB(buf, 0);
    if (t + 1 < nt) stA(t + 1, 1);
    __builtin_amdgcn_s_barrier();
    LGK0();
    __builtin_amdgcn_s_setprio(1); MFMAQ(0); __builtin_amdgcn_s_setprio(0);
    __builtin_amdgcn_s_barrier();
    LOADA(buf, 0, 1);
    if (t + 1 < nt) stB(t + 1, 1);
    __builtin_amdgcn_s_barrier();
    LGK0();
    __builtin_amdgcn_s_setprio(1); MFMAQ(1); __builtin_amdgcn_s_setprio(0);
    __builtin_amdgcn_s_barrier();
    LOADA(buf, 1, 0); LOADB(buf, 1);
    if (t + 2 < nt) stA(t + 2, 0);
    __builtin_amdgcn_s_barrier();
    LGK0();
    __builtin_amdgcn_s_setprio(1); MFMAQ(0); __builtin_amdgcn_s_setprio(0);
    __builtin_amdgcn_s_barrier();
    LOADA(buf, 1, 1);
    if (t + 2 < nt) stB(t + 2, 0);
    __builtin_amdgcn_s_barrier();
    LGK0();
    __builtin_amdgcn_s_setprio(1); MFMAQ(1); __builtin_amdgcn_s_setprio(0);
    if (t + 1 < nt) {
      if (t + 2 < nt) { asm volatile("s_waitcnt vmcnt(4)" ::: "memory"); }
      else            { asm volatile("s_waitcnt vmcnt(0)" ::: "memory"); }
      __builtin_amdgcn_s_barrier();
    }
  }
#undef LOADA
#undef LOADB
#undef MFMAQ
#undef LGK0

#pragma unroll
  for (int i = 0; i < 8; ++i)
#pragma unroll
    for (int j = 0; j < 4; ++j)
#pragma unroll
      for (int r = 0; r < 4; ++r) {
        int m = m0 + wr * 128 + i * 16 + ((lane >> 4) << 2) + r;
        int n = n0 + wc * 64 + j * 16 + (lane & 15);
        float v = acc[i][j][r];
        if (MODE == 0) {
          unsigned short* dst = outb + ((n >= 1024) ? 4194304 : 0);
          int nn = n & 1023;
          int bb = m >> 11, s = m & 2047, hh = nn >> 6, dd = nn & 63;
          dst[(((size_t)bb * 16 + hh) * 2048 + s) * 64 + dd] = f2bf(v);
        } else if (MODE == 1) {
          int hh = m >> 6, dd = m & 63, bb = n >> 11, s = n & 2047;
          outb[(((size_t)bb * 16 + hh) * 64 + dd) * 2048 + s] = f2bf(v);
        } else if (MODE == 2) {
          size_t idx = (size_t)m * 1024 + n;
          outf[idx] = resid[idx] + v;
        } else if (MODE == 3) {
          outb[(size_t)m * 4096 + n] = f2bf(v);
        } else if (MODE == 4) {
          size_t idx = (size_t)m * 4096 + n;
          float g = bf2f(gate[idx]);
          outb[idx] = f2bf(g / (1.0f + __expf(-g)) * v);
        } else {
          outf[(size_t)m * 1024 + n] = v;
        }
      }
}

DEV void swz_map(int bid, int nwg, int MT, int& bm, int& bn) {
  int cpx = nwg >> 3;
  int sw = (bid & 7) * cpx + (bid >> 3);
  bm = sw % MT;
  bn = sw / MT;
}

template <int MODE>
__global__ __launch_bounds__(512, 2) void gemm8_k(const unsigned short* __restrict__ A, int lda,
                                                  const unsigned short* __restrict__ B, int ldb,
                                                  int MT, int kz, int nt,
                                                  unsigned short* __restrict__ outb,
                                                  float* __restrict__ outf,
                                                  const float* __restrict__ resid,
                                                  const unsigned short* __restrict__ gate) {
  __shared__ __align__(16) unsigned short lds[65536];
  int bm, bn;
  swz_map(blockIdx.x, gridDim.x, MT, bm, bn);
  int kb = kz * blockIdx.y;
  float* of = outf;
  if (MODE == 5) of += (size_t)blockIdx.y * 4194304;
  gemm8_body<MODE>(A, lda, B, ldb, bm, bn, kb, nt, outb, of, resid, gate, lds, lds + 32768);
}

__global__ __launch_bounds__(512, 2) void gemm8_qkv(const unsigned short* __restrict__ xn,
                                                    const unsigned short* __restrict__ wqk,
                                                    const unsigned short* __restrict__ wv,
                                                    unsigned short* __restrict__ qk_out,
                                                    unsigned short* __restrict__ vt_out) {
  __shared__ __align__(16) unsigned short lds[65536];
  int bid = blockIdx.x;
  if (bid < 128) {
    int bm, bn;
    swz_map(bid, 128, 16, bm, bn);
    gemm8_body<0>(xn, 1024, wqk, 1024, bm, bn, 0, 16, qk_out, nullptr, nullptr, nullptr, lds, lds + 32768);
  } else {
    bid -= 128;
    int bm, bn;
    swz_map(bid, 64, 4, bm, bn);
    gemm8_body<1>(wv, 1024, xn, 1024, bm, bn, 0, 16, vt_out, nullptr, nullptr, nullptr, lds, lds + 32768);
  }
}

// ---------------- 128x128 2-phase GEMM for wo (full 256-block fill) ----------------
__global__ __launch_bounds__(256) void gemm_wo(const unsigned short* __restrict__ A,
                                               const unsigned short* __restrict__ Bw,
                                               float* __restrict__ outf,
                                               const float* __restrict__ resid) {
  __shared__ __align__(16) unsigned short As[128 * 64];
  __shared__ __align__(16) unsigned short Bs[128 * 64];
  const int K = 1024, N = 1024;
  const int tid = threadIdx.x;
  const int wid = tid >> 6, lane = tid & 63;
  const int wr = wid >> 1, wc = wid & 1;
  const int m0 = blockIdx.x * 128, n0 = blockIdx.y * 128;
  const int sw = (lane & 7) * 8;
  f32x4 acc[4][4] = {};

  for (int k0 = 0; k0 < K; k0 += 64) {
    __syncthreads();
#pragma unroll
    for (int it = 0; it < 4; ++it) {
      int c = wid * 4 + it;
      int row = c * 8 + (lane >> 3);
      int col = ((lane & 7) ^ (row & 7)) * 8;
      gload_lds16(A + (size_t)(m0 + row) * K + k0 + col, As + c * 512);
      gload_lds16(Bw + (size_t)(n0 + row) * K + k0 + col, Bs + c * 512);
    }
    asm volatile("s_waitcnt vmcnt(0)" ::: "memory");
    __syncthreads();
#pragma unroll
    for (int kk = 0; kk < 2; ++kk) {
      const int kof = (kk * 32 + (lane >> 4) * 8) ^ sw;
      bf16x8 af[4], bfr[4];
#pragma unroll
      for (int i = 0; i < 4; ++i) {
        af[i]  = *(const bf16x8*)(As + (wr * 64 + i * 16 + (lane & 15)) * 64 + kof);
        bfr[i] = *(const bf16x8*)(Bs + (wc * 64 + i * 16 + (lane & 15)) * 64 + kof);
      }
#pragma unroll
      for (int i = 0; i < 4; ++i)
#pragma unroll
        for (int j = 0; j < 4; ++j) acc[i][j] = mfma16(af[i], bfr[j], acc[i][j]);
    }
  }
  const int rb = m0 + wr * 64 + ((lane >> 4) * 4);
  const int cb = n0 + wc * 64 + (lane & 15);
#pragma unroll
  for (int i = 0; i < 4; ++i)
#pragma unroll
    for (int r = 0; r < 4; ++r) {
      int m = rb + i * 16 + r;
#pragma unroll
      for (int j = 0; j < 4; ++j) {
        size_t idx = (size_t)m * N + cb + j * 16;
        outf[idx] = resid[idx] + acc[i][j][r];
      }
    }
}

// ---------------- w2 split-K reduce ----------------
__global__ __launch_bounds__(256) void reduce_k(float* __restrict__ out,
                                                const float* __restrict__ part) {
  int i = (blockIdx.x * 256 + threadIdx.x) * 4;
  float4 o = *(const float4*)(out + i);
  float4 p0 = *(const float4*)(part + i);
  float4 p1 = *(const float4*)(part + 4194304 + i);
  float4 p2 = *(const float4*)(part + 8388608 + i);
  float4 p3 = *(const float4*)(part + 12582912 + i);
  o.x += p0.x + p1.x + p2.x + p3.x;
  o.y += p0.y + p1.y + p2.y + p3.y;
  o.z += p0.z + p1.z + p2.z + p3.z;
  o.w += p0.w + p1.w + p2.w + p3.w;
  *(float4*)(out + i) = o;
}

// ---------------- Flash attention: XCD-pinned, double-buffered, log2 softmax ----------------
__global__ __launch_bounds__(256) void attn_k(const unsigned short* __restrict__ q,
                                              const unsigned short* __restrict__ k,
                                              const unsigned short* __restrict__ vt,
                                              unsigned short* __restrict__ ctx) {
  __shared__ __align__(16) unsigned short Ks[2][64 * 64];
  __shared__ __align__(16) unsigned short Vs[2][64 * 64];
  __shared__ __align__(16) unsigned short Ps[4][16 * 72];
  const int bid = blockIdx.x;            // 512 blocks
  const int bh = (bid & 7) * 4 + ((bid >> 3) & 3);  // 4 heads per XCD
  const int p = bid >> 5;                 // 0..15, paired q-tiles
  const int tid = threadIdx.x, wid = tid >> 6, lane = tid & 63;
  const size_t bhS = (size_t)bh * 2048;
  const size_t bhD = (size_t)bh * 64 * 2048;
  const int b = bh >> 4, hh = bh & 15;
  const int sw = (lane & 7) * 8;
  const float SC2 = 0.18033688011112042f;  // 0.125 * log2(e)

  const int c0 = wid * 2, c1 = wid * 2 + 1;
  const int row0 = c0 * 8 + (lane >> 3), row1 = c1 * 8 + (lane >> 3);
  const int col0 = ((lane & 7) ^ (row0 & 7)) * 8;
  const int col1 = ((lane & 7) ^ (row1 & 7)) * 8;

  auto stage = [&](int kt, int buf) {
    gload_lds16(k + (bhS + kt * 64 + row0) * 64 + col0, &Ks[buf][c0 * 512]);
    gload_lds16(k + (bhS + kt * 64 + row1) * 64 + col1, &Ks[buf][c1 * 512]);
    gload_lds16(vt + bhD + (size_t)row0 * 2048 + kt * 64 + col0, &Vs[buf][c0 * 512]);
    gload_lds16(vt + bhD + (size_t)row1 * 2048 + kt * 64 + col1, &Vs[buf][c1 * 512]);
  };

  for (int half = 0; half < 2; ++half) {
    const int qt = half ? (31 - p) : p;
    const int q0 = qt * 64;

    bf16x8 qf[2];
    {
      const unsigned short* qp = q + (bhS + q0 + wid * 16 + (lane & 15)) * 64 + (lane >> 4) * 8;
      qf[0] = *(const bf16x8*)qp;
      qf[1] = *(const bf16x8*)(qp + 32);
    }
    float mrow[4], lrow[4];
    f32x4 o[4] = {};
#pragma unroll
    for (int r = 0; r < 4; ++r) { mrow[r] = -1e30f; lrow[r] = 0.0f; }
    const int rowb = q0 + wid * 16 + ((lane >> 4) * 4);

    // prologue: stage tiles 0 (and 1)
    stage(0, 0);
    if (qt > 0) { stage(1, 1); asm volatile("s_waitcnt vmcnt(4)" ::: "memory"); }
    else        {              asm volatile("s_waitcnt vmcnt(0)" ::: "memory"); }
    __builtin_amdgcn_s_barrier();

    for (int kt = 0; kt <= qt; ++kt) {
      const int cur = kt & 1;
      // QK^T
      f32x4 s[4];
#pragma unroll
      for (int nt = 0; nt < 4; ++nt) {
        f32x4 z = {};
#pragma unroll
        for (int ks = 0; ks < 2; ++ks) {
          int kof = (ks * 32 + (lane >> 4) * 8) ^ sw;
          bf16x8 kf = *(const bf16x8*)(&Ks[cur][(nt * 16 + (lane & 15)) * 64 + kof]);
          z = mfma16(qf[ks], kf, z);
        }
        s[nt] = z;
      }
      // log2-domain online softmax with defer-max
      const bool diag = (kt == qt);
      float pm[4];
      bool ok = true;
#pragma unroll
      for (int r = 0; r < 4; ++r) {
        float mx = -3e38f;
#pragma unroll
        for (int nt = 0; nt < 4; ++nt) {
          float val = s[nt][r] * SC2;
          if (diag && (kt * 64 + nt * 16 + (lane & 15)) > (rowb + r)) val = -3e38f;
          s[nt][r] = val;
          mx = fmaxf(mx, val);
        }
        mx = fmaxf(mx, __shfl_xor(mx, 1));
        mx = fmaxf(mx, __shfl_xor(mx, 2));
        mx = fmaxf(mx, __shfl_xor(mx, 4));
        mx = fmaxf(mx, __shfl_xor(mx, 8));
        pm[r] = mx;
        ok = ok && (mx <= mrow[r] + 11.5f);
      }
      if (!__all(ok)) {
#pragma unroll
        for (int r = 0; r < 4; ++r) {
          float mn = fmaxf(mrow[r], pm[r]);
          float al = fexp2(mrow[r] - mn);
          lrow[r] *= al;
#pragma unroll
          for (int d = 0; d < 4; ++d) o[d][r] *= al;
          mrow[r] = mn;
        }
      }
#pragma unroll
      for (int r = 0; r < 4; ++r) {
        float sum = 0.0f;
#pragma unroll
        for (int nt = 0; nt < 4; ++nt) {
          float pv = fexp2(s[nt][r] - mrow[r]);
          s[nt][r] = pv;
          sum += pv;
        }
        lrow[r] += sum;   // per-lane partial; reduced after the loop
      }
      // P -> wave-private LDS (no block barrier needed)
#pragma unroll
      for (int nt = 0; nt < 4; ++nt)
#pragma unroll
        for (int r = 0; r < 4; ++r)
          Ps[wid][((lane >> 4) * 4 + r) * 72 + nt * 16 + (lane & 15)] = f2bf(s[nt][r]);
      // PV
#pragma unroll
      for (int ks = 0; ks < 2; ++ks) {
        bf16x8 pf = *(const bf16x8*)(&Ps[wid][(lane & 15) * 72 + ks * 32 + (lane >> 4) * 8]);
        int kof = (ks * 32 + (lane >> 4) * 8) ^ sw;
#pragma unroll
        for (int d = 0; d < 4; ++d) {
          bf16x8 vf = *(const bf16x8*)(&Vs[cur][(d * 16 + (lane & 15)) * 64 + kof]);
          o[d] = mfma16(pf, vf, o[d]);
        }
      }
      __builtin_amdgcn_s_barrier();      // all waves done reading buf[cur]
      if (kt + 2 <= qt) {
        stage(kt + 2, cur);
        asm volatile("s_waitcnt vmcnt(4)" ::: "memory");   // tile kt+1 landed
      } else if (kt + 1 <= qt) {
        asm volatile("s_waitcnt vmcnt(0)" ::: "memory");
      }
      __builtin_amdgcn_s_barrier();
    }
    // reduce per-lane lrow partials across the 16-lane row group
#pragma unroll
    for (int r = 0; r < 4; ++r) {
      lrow[r] += __shfl_xor(lrow[r], 1);
      lrow[r] += __shfl_xor(lrow[r], 2);
      lrow[r] += __shfl_xor(lrow[r], 4);
      lrow[r] += __shfl_xor(lrow[r], 8);
    }
#pragma unroll
    for (int d = 0; d < 4; ++d)
#pragma unroll
      for (int r = 0; r < 4; ++r) {
        float val = o[d][r] / lrow[r];
        ctx[((size_t)b * 2048 + (rowb + r)) * 1024 + hh * 64 + d * 16 + (lane & 15)] = f2bf(val);
      }
  }
}

extern "C" void kernel_launch(void* const* d_in, const int* in_sizes, int n_in,
                              void* d_out, int out_size, void* d_ws, size_t ws_size,
                              hipStream_t stream) {
  (void)in_sizes; (void)n_in; (void)out_size; (void)ws_size;
  const float* in_f = (const float*)d_in[0];
  const int* pos    = (const int*)d_in[1];
  const float* q_w  = (const float*)d_in[2];
  const float* k_w  = (const float*)d_in[3];
  const float* v_w  = (const float*)d_in[4];
  const float* o_w  = (const float*)d_in[5];
  const float* ln1  = (const float*)d_in[6];
  const float* ln2  = (const float*)d_in[7];
  const float* w1   = (const float*)d_in[8];
  const float* w2   = (const float*)d_in[9];
  const float* w3   = (const float*)d_in[10];
  float* out = (float*)d_out;

  unsigned short* ws = (unsigned short*)d_ws;
  unsigned short* wb   = ws;
  unsigned short* wqkb = wb;
  unsigned short* wvb  = wb + 2097152;
  unsigned short* wob  = wb + 3145728;
  unsigned short* w1b  = wb + 4194304;
  unsigned short* w2b  = wb + 8388608;
  unsigned short* w3b  = wb + 12582912;
  unsigned short* xn   = ws + 16777216;
  unsigned short* qb   = ws + 20971520;
  unsigned short* kb   = ws + 25165824;   // must be qb + 4194304
  unsigned short* vb   = ws + 29360128;   // V^T [bh][64][2048]
  unsigned short* cx   = ws + 33554432;
  unsigned short* gb   = ws + 37748736;
  float* part          = (float*)(ws + 20971520);  // aliases qb..gb (dead by w2)
  unsigned short* hb   = ws + 54525952;

  CvtArgs ca;
  ca.src[0] = q_w; ca.src[1] = k_w; ca.src[2] = v_w; ca.src[3] = o_w;
  ca.src[4] = w1;  ca.src[5] = w2;  ca.src[6] = w3;
  ca.cum[0] = 0;        ca.cum[1] = 1048576;  ca.cum[2] = 2097152;  ca.cum[3] = 3145728;
  ca.cum[4] = 4194304;  ca.cum[5] = 8388608;  ca.cum[6] = 12582912; ca.cum[7] = 16777216;
  cvt_all<<<16384, 256, 0, stream>>>(ca, wb);

  rmsnorm_k<<<4096, 256, 0, stream>>>(in_f, ln1, xn);

  gemm8_qkv<<<192, 512, 0, stream>>>(xn, wqkb, wvb, qb, vb);

  rope2_k<<<16384, 256, 0, stream>>>(qb, kb, pos);

  attn_k<<<512, 256, 0, stream>>>(qb, kb, vb, cx);

  gemm_wo<<<dim3(32, 8), 256, 0, stream>>>(cx, wob, out, in_f);

  rmsnorm_k<<<4096, 256, 0, stream>>>(out, ln2, xn);

  gemm8_k<3><<<256, 512, 0, stream>>>(xn, 1024, w1b, 1024, 16, 0, 16, gb, nullptr, nullptr, nullptr);
  gemm8_k<4><<<256, 512, 0, stream>>>(xn, 1024, w3b, 1024, 16, 0, 16, hb, nullptr, nullptr, gb);
  gemm8_k<5><<<dim3(64, 4), 512, 0, stream>>>(hb, 4096, w2b, 4096, 16, 1024, 16, nullptr, part, nullptr, nullptr);

  reduce_k<<<4096, 256, 0, stream>>>(out, part);
}

// Round 5
// 294.439 us; speedup vs baseline: 1.7550x; 1.0057x over previous
//
#include <hip/hip_runtime.h>
#include <hip/hip_bf16.h>

typedef __attribute__((ext_vector_type(8))) __bf16 bf16x8;
typedef __attribute__((ext_vector_type(4))) float f32x4;

#define DEV static __device__ __forceinline__

DEV unsigned short f2bf(float f) {
  __bf16 h = (__bf16)f;                  // compiles to v_cvt_pk_bf16_f32 (RNE)
  union { __bf16 h; unsigned short u; } v; v.h = h;
  return v.u;
}
DEV float bf2f(unsigned short h) {
  union { unsigned int u; float f; } v; v.u = ((unsigned int)h) << 16;
  return v.f;
}
DEV f32x4 mfma16(bf16x8 a, bf16x8 b, f32x4 c) {
  return __builtin_amdgcn_mfma_f32_16x16x32_bf16(a, b, c, 0, 0, 0);
}
DEV void gload_lds16(const void* g, void* l) {
  __builtin_amdgcn_global_load_lds((__attribute__((address_space(1))) void*)g,
                                   (__attribute__((address_space(3))) void*)l,
                                   16, 0, 0);
}
#if __has_builtin(__builtin_amdgcn_exp2f)
DEV float fexp2(float x) { return __builtin_amdgcn_exp2f(x); }
#else
DEV float fexp2(float x) { return exp2f(x); }
#endif

// ---------------- fused f32 -> bf16 convert of all 7 weights ----------------
struct CvtArgs { const float* src[7]; int cum[8]; };
__global__ __launch_bounds__(256) void cvt_all(CvtArgs a, unsigned short* __restrict__ dst) {
  int i = (blockIdx.x * 256 + threadIdx.x) * 4;
  if (i >= a.cum[7]) return;
  int w = 0;
#pragma unroll 7
  for (int t = 0; t < 7; ++t) if (i >= a.cum[t + 1]) w = t + 1;
  float4 v = *(const float4*)(a.src[w] + (i - a.cum[w]));
  dst[i + 0] = f2bf(v.x);
  dst[i + 1] = f2bf(v.y);
  dst[i + 2] = f2bf(v.z);
  dst[i + 3] = f2bf(v.w);
}

// ---------------- RMSNorm: fp32 in -> bf16 out (D=1024) ----------------
__global__ __launch_bounds__(256) void rmsnorm_k(const float* __restrict__ x,
                                                 const float* __restrict__ w,
                                                 unsigned short* __restrict__ out) {
  int row = blockIdx.x;
  int tid = threadIdx.x;
  const float* xr = x + (size_t)row * 1024;
  float4 v = *(const float4*)(xr + tid * 4);
  float ss = v.x * v.x + v.y * v.y + v.z * v.z + v.w * v.w;
#pragma unroll
  for (int m = 32; m >= 1; m >>= 1) ss += __shfl_xor(ss, m);
  __shared__ float red[4];
  int wid = tid >> 6;
  if ((tid & 63) == 0) red[wid] = ss;
  __syncthreads();
  float tot = red[0] + red[1] + red[2] + red[3];
  float rs = rsqrtf(tot * (1.0f / 1024.0f) + 1e-5f);
  float4 wv = *(const float4*)(w + tid * 4);
  unsigned short* o = out + (size_t)row * 1024 + tid * 4;
  o[0] = f2bf(v.x * rs * wv.x);
  o[1] = f2bf(v.y * rs * wv.y);
  o[2] = f2bf(v.z * rs * wv.z);
  o[3] = f2bf(v.w * rs * wv.w);
}

// ---------------- RoPE in-place on q and k, [BH=32][S=2048][64] bf16 ----------------
__global__ __launch_bounds__(256) void rope2_k(unsigned short* __restrict__ q,
                                               unsigned short* __restrict__ k,
                                               const int* __restrict__ pos) {
  int gid = blockIdx.x * 256 + threadIdx.x;
  unsigned short* x = (gid < 2097152) ? q : k;
  int idx = gid & 2097151;
  int i = idx & 31;
  int s = (idx >> 5) & 2047;
  int bh = idx >> 16;
  int b = bh >> 4;
  float p = (float)pos[b * 2048 + s];
  float inv = exp2f(-(float)i * 0.4152410118609203f);
  float ang = p * inv;
  float sn = sinf(ang), cs = cosf(ang);
  size_t base = (((size_t)bh * 2048) + s) * 64 + 2 * i;
  float x1 = bf2f(x[base]), x2 = bf2f(x[base + 1]);
  x[base]     = f2bf(x1 * cs - x2 * sn);
  x[base + 1] = f2bf(x1 * sn + x2 * cs);
}

// ================= 256x256 8-phase GEMM =================
template <int MODE>
DEV void gemm8_body(const unsigned short* __restrict__ A, int lda,
                    const unsigned short* __restrict__ B, int ldb,
                    int bm, int bn, int kbase, int nt,
                    unsigned short* __restrict__ outb, float* __restrict__ outf,
                    const float* __restrict__ resid, const unsigned short* __restrict__ gate,
                    unsigned short* As, unsigned short* Bs) {
  const int tid = threadIdx.x;
  const int lane = tid & 63, wid = tid >> 6;
  const int wr = wid >> 2, wc = wid & 3;
  const int m0 = bm * 256, n0 = bn * 256;

  const int r0 = tid >> 2, r1 = 128 + (tid >> 2), cc = tid & 3;
  const int sc0 = (cc ^ ((r0 >> 1) & 3)) * 8;
  const int sc1 = (cc ^ ((r1 >> 1) & 3)) * 8;
  const size_t arow0 = (size_t)(m0 + r0) * lda, arow1 = (size_t)(m0 + r1) * lda;
  const size_t brow0 = (size_t)(n0 + r0) * ldb, brow1 = (size_t)(n0 + r1) * ldb;
  const int du0 = tid * 8, du1 = (512 + tid) * 8;

  auto stA = [&](int t, int kh) {
    unsigned short* d = As + ((((t & 1) << 1) | kh) * 8192);
    const unsigned short* s = A + kbase + t * 64 + kh * 32;
    gload_lds16(s + arow0 + sc0, d + du0);
    gload_lds16(s + arow1 + sc1, d + du1);
  };
  auto stB = [&](int t, int kh) {
    unsigned short* d = Bs + ((((t & 1) << 1) | kh) * 8192);
    const unsigned short* s = B + kbase + t * 64 + kh * 32;
    gload_lds16(s + brow0 + sc0, d + du0);
    gload_lds16(s + brow1 + sc1, d + du1);
  };

  const int fcol = ((lane >> 4) ^ ((lane >> 1) & 3)) * 8;
  const int frow = lane & 15;
  const int abase = (wr * 128 + frow) * 32 + fcol;
  const int bbase = (wc * 64 + frow) * 32 + fcol;

  f32x4 acc[8][4] = {};
  bf16x8 a[4], b[4];

#define LOADA(buf, ks, mh) { const unsigned short* p_ = As + (((buf) << 1) | (ks)) * 8192 + abase + (mh) * 2048; \
  a[0] = *(const bf16x8*)(p_); a[1] = *(const bf16x8*)(p_ + 512); \
  a[2] = *(const bf16x8*)(p_ + 1024); a[3] = *(const bf16x8*)(p_ + 1536); }
#define LOADB(buf, ks) { const unsigned short* p_ = Bs + (((buf) << 1) | (ks)) * 8192 + bbase; \
  b[0] = *(const bf16x8*)(p_); b[1] = *(const bf16x8*)(p_ + 512); \
  b[2] = *(const bf16x8*)(p_ + 1024); b[3] = *(const bf16x8*)(p_ + 1536); }
#define MFMAQ(mh) { _Pragma("unroll") for (int fi = 0; fi < 4; ++fi) \
  _Pragma("unroll") for (int j = 0; j < 4; ++j) \
    acc[(mh) * 4 + fi][j] = mfma16(a[fi], b[j], acc[(mh) * 4 + fi][j]); }
#define LGK0() { asm volatile("s_waitcnt lgkmcnt(0)" ::: "memory"); __builtin_amdgcn_sched_barrier(0); }

  stA(0, 0); stB(0, 0); stA(0, 1); stB(0, 1);
  stA(1, 0); stB(1, 0);
  asm volatile("s_waitcnt vmcnt(4)" ::: "memory");
  __builtin_amdgcn_s_barrier();

  for (int t = 0; t < nt; ++t) {
    const int buf = t & 1;
    LOADA(buf, 0, 0); LOADB(buf, 0);
    if (t + 1 < nt) stA(t + 1, 1);
    __builtin_amdgcn_s_barrier();
    LGK0();
    __builtin_amdgcn_s_setprio(1); MFMAQ(0); __builtin_amdgcn_s_setprio(0);
    __builtin_amdgcn_s_barrier();
    LOADA(buf, 0, 1);
    if (t + 1 < nt) stB(t + 1, 1);
    __builtin_amdgcn_s_barrier();
    LGK0();
    __builtin_amdgcn_s_setprio(1); MFMAQ(1); __builtin_amdgcn_s_setprio(0);
    __builtin_amdgcn_s_barrier();
    LOADA(buf, 1, 0); LOADB(buf, 1);
    if (t + 2 < nt) stA(t + 2, 0);
    __builtin_amdgcn_s_barrier();
    LGK0();
    __builtin_amdgcn_s_setprio(1); MFMAQ(0); __builtin_amdgcn_s_setprio(0);
    __builtin_amdgcn_s_barrier();
    LOADA(buf, 1, 1);
    if (t + 2 < nt) stB(t + 2, 0);
    __builtin_amdgcn_s_barrier();
    LGK0();
    __builtin_amdgcn_s_setprio(1); MFMAQ(1); __builtin_amdgcn_s_setprio(0);
    if (t + 1 < nt) {
      if (t + 2 < nt) { asm volatile("s_waitcnt vmcnt(4)" ::: "memory"); }
      else            { asm volatile("s_waitcnt vmcnt(0)" ::: "memory"); }
      __builtin_amdgcn_s_barrier();
    }
  }
#undef LOADA
#undef LOADB
#undef MFMAQ
#undef LGK0

#pragma unroll
  for (int i = 0; i < 8; ++i)
#pragma unroll
    for (int j = 0; j < 4; ++j)
#pragma unroll
      for (int r = 0; r < 4; ++r) {
        int m = m0 + wr * 128 + i * 16 + ((lane >> 4) << 2) + r;
        int n = n0 + wc * 64 + j * 16 + (lane & 15);
        float v = acc[i][j][r];
        if (MODE == 0) {
          unsigned short* dst = outb + ((n >= 1024) ? 4194304 : 0);
          int nn = n & 1023;
          int bb = m >> 11, s = m & 2047, hh = nn >> 6, dd = nn & 63;
          dst[(((size_t)bb * 16 + hh) * 2048 + s) * 64 + dd] = f2bf(v);
        } else if (MODE == 1) {
          int hh = m >> 6, dd = m & 63, bb = n >> 11, s = n & 2047;
          outb[(((size_t)bb * 16 + hh) * 64 + dd) * 2048 + s] = f2bf(v);
        } else if (MODE == 2) {
          size_t idx = (size_t)m * 1024 + n;
          outf[idx] = resid[idx] + v;
        } else if (MODE == 3) {
          outb[(size_t)m * 4096 + n] = f2bf(v);
        } else if (MODE == 4) {
          size_t idx = (size_t)m * 4096 + n;
          float g = bf2f(gate[idx]);
          outb[idx] = f2bf(g / (1.0f + __expf(-g)) * v);
        } else {
          outf[(size_t)m * 1024 + n] = v;
        }
      }
}

DEV void swz_map(int bid, int nwg, int MT, int& bm, int& bn) {
  int cpx = nwg >> 3;
  int sw = (bid & 7) * cpx + (bid >> 3);
  bm = sw % MT;
  bn = sw / MT;
}

template <int MODE>
__global__ __launch_bounds__(512, 2) void gemm8_k(const unsigned short* __restrict__ A, int lda,
                                                  const unsigned short* __restrict__ B, int ldb,
                                                  int MT, int kz, int nt,
                                                  unsigned short* __restrict__ outb,
                                                  float* __restrict__ outf,
                                                  const float* __restrict__ resid,
                                                  const unsigned short* __restrict__ gate) {
  __shared__ __align__(16) unsigned short lds[65536];
  int bm, bn;
  swz_map(blockIdx.x, gridDim.x, MT, bm, bn);
  int kb = kz * blockIdx.y;
  float* of = outf;
  if (MODE == 5) of += (size_t)blockIdx.y * 4194304;
  gemm8_body<MODE>(A, lda, B, ldb, bm, bn, kb, nt, outb, of, resid, gate, lds, lds + 32768);
}

__global__ __launch_bounds__(512, 2) void gemm8_qkv(const unsigned short* __restrict__ xn,
                                                    const unsigned short* __restrict__ wqk,
                                                    const unsigned short* __restrict__ wv,
                                                    unsigned short* __restrict__ qk_out,
                                                    unsigned short* __restrict__ vt_out) {
  __shared__ __align__(16) unsigned short lds[65536];
  int bid = blockIdx.x;
  if (bid < 128) {
    int bm, bn;
    swz_map(bid, 128, 16, bm, bn);
    gemm8_body<0>(xn, 1024, wqk, 1024, bm, bn, 0, 16, qk_out, nullptr, nullptr, nullptr, lds, lds + 32768);
  } else {
    bid -= 128;
    int bm, bn;
    swz_map(bid, 64, 4, bm, bn);
    gemm8_body<1>(wv, 1024, xn, 1024, bm, bn, 0, 16, vt_out, nullptr, nullptr, nullptr, lds, lds + 32768);
  }
}

// ---------------- 128x128 2-phase GEMM for wo (full 256-block fill) ----------------
__global__ __launch_bounds__(256) void gemm_wo(const unsigned short* __restrict__ A,
                                               const unsigned short* __restrict__ Bw,
                                               float* __restrict__ outf,
                                               const float* __restrict__ resid) {
  __shared__ __align__(16) unsigned short As[128 * 64];
  __shared__ __align__(16) unsigned short Bs[128 * 64];
  const int K = 1024, N = 1024;
  const int tid = threadIdx.x;
  const int wid = tid >> 6, lane = tid & 63;
  const int wr = wid >> 1, wc = wid & 1;
  const int m0 = blockIdx.x * 128, n0 = blockIdx.y * 128;
  const int sw = (lane & 7) * 8;
  f32x4 acc[4][4] = {};

  for (int k0 = 0; k0 < K; k0 += 64) {
    __syncthreads();
#pragma unroll
    for (int it = 0; it < 4; ++it) {
      int c = wid * 4 + it;
      int row = c * 8 + (lane >> 3);
      int col = ((lane & 7) ^ (row & 7)) * 8;
      gload_lds16(A + (size_t)(m0 + row) * K + k0 + col, As + c * 512);
      gload_lds16(Bw + (size_t)(n0 + row) * K + k0 + col, Bs + c * 512);
    }
    asm volatile("s_waitcnt vmcnt(0)" ::: "memory");
    __syncthreads();
#pragma unroll
    for (int kk = 0; kk < 2; ++kk) {
      const int kof = (kk * 32 + (lane >> 4) * 8) ^ sw;
      bf16x8 af[4], bfr[4];
#pragma unroll
      for (int i = 0; i < 4; ++i) {
        af[i]  = *(const bf16x8*)(As + (wr * 64 + i * 16 + (lane & 15)) * 64 + kof);
        bfr[i] = *(const bf16x8*)(Bs + (wc * 64 + i * 16 + (lane & 15)) * 64 + kof);
      }
#pragma unroll
      for (int i = 0; i < 4; ++i)
#pragma unroll
        for (int j = 0; j < 4; ++j) acc[i][j] = mfma16(af[i], bfr[j], acc[i][j]);
    }
  }
  const int rb = m0 + wr * 64 + ((lane >> 4) * 4);
  const int cb = n0 + wc * 64 + (lane & 15);
#pragma unroll
  for (int i = 0; i < 4; ++i)
#pragma unroll
    for (int r = 0; r < 4; ++r) {
      int m = rb + i * 16 + r;
#pragma unroll
      for (int j = 0; j < 4; ++j) {
        size_t idx = (size_t)m * N + cb + j * 16;
        outf[idx] = resid[idx] + acc[i][j][r];
      }
    }
}

// ---------------- w2 split-K reduce ----------------
__global__ __launch_bounds__(256) void reduce_k(float* __restrict__ out,
                                                const float* __restrict__ part) {
  int i = (blockIdx.x * 256 + threadIdx.x) * 4;
  float4 o = *(const float4*)(out + i);
  float4 p0 = *(const float4*)(part + i);
  float4 p1 = *(const float4*)(part + 4194304 + i);
  float4 p2 = *(const float4*)(part + 8388608 + i);
  float4 p3 = *(const float4*)(part + 12582912 + i);
  o.x += p0.x + p1.x + p2.x + p3.x;
  o.y += p0.y + p1.y + p2.y + p3.y;
  o.z += p0.z + p1.z + p2.z + p3.z;
  o.w += p0.w + p1.w + p2.w + p3.w;
  *(float4*)(out + i) = o;
}

// ---------------- Flash attention: XCD-pinned, 1024 blocks, dbuf, log2 softmax ----------------
__global__ __launch_bounds__(256) void attn_k(const unsigned short* __restrict__ q,
                                              const unsigned short* __restrict__ k,
                                              const unsigned short* __restrict__ vt,
                                              unsigned short* __restrict__ ctx) {
  __shared__ __align__(16) unsigned short Ks[2][64 * 64];
  __shared__ __align__(16) unsigned short Vs[2][64 * 64];
  __shared__ __align__(16) unsigned short Ps[4][16 * 64];   // XOR-swizzled
  const int bid = blockIdx.x;                    // 1024 blocks
  const int bh = (bid & 7) * 4 + ((bid >> 3) & 3);  // 4 heads per XCD
  const int qt = 31 - (bid >> 5);                 // longest blocks first
  const int tid = threadIdx.x, wid = tid >> 6, lane = tid & 63;
  const size_t bhS = (size_t)bh * 2048;
  const size_t bhD = (size_t)bh * 64 * 2048;
  const int b = bh >> 4, hh = bh & 15;
  const int sw = (lane & 7) * 8;
  const float SC2 = 0.18033688011112042f;  // 0.125 * log2(e)

  const int c0 = wid * 2, c1 = wid * 2 + 1;
  const int row0 = c0 * 8 + (lane >> 3), row1 = c1 * 8 + (lane >> 3);
  const int col0 = ((lane & 7) ^ (row0 & 7)) * 8;
  const int col1 = ((lane & 7) ^ (row1 & 7)) * 8;

  auto stage = [&](int kt, int buf) {
    gload_lds16(k + (bhS + kt * 64 + row0) * 64 + col0, &Ks[buf][c0 * 512]);
    gload_lds16(k + (bhS + kt * 64 + row1) * 64 + col1, &Ks[buf][c1 * 512]);
    gload_lds16(vt + bhD + (size_t)row0 * 2048 + kt * 64 + col0, &Vs[buf][c0 * 512]);
    gload_lds16(vt + bhD + (size_t)row1 * 2048 + kt * 64 + col1, &Vs[buf][c1 * 512]);
  };

  const int q0 = qt * 64;
  bf16x8 qf[2];
  {
    const unsigned short* qp = q + (bhS + q0 + wid * 16 + (lane & 15)) * 64 + (lane >> 4) * 8;
    qf[0] = *(const bf16x8*)qp;
    qf[1] = *(const bf16x8*)(qp + 32);
    // fold softmax scale into Q (bf16 re-round: ok under bf16 tolerance)
#pragma unroll
    for (int jj = 0; jj < 8; ++jj) {
      qf[0][jj] = (__bf16)((float)qf[0][jj] * SC2);
      qf[1][jj] = (__bf16)((float)qf[1][jj] * SC2);
    }
  }
  float mrow[4], lrow[4];
  f32x4 o[4] = {};
#pragma unroll
  for (int r = 0; r < 4; ++r) { mrow[r] = -1e30f; lrow[r] = 0.0f; }
  const int rowb = q0 + wid * 16 + ((lane >> 4) * 4);

  stage(0, 0);
  if (qt > 0) { stage(1, 1); asm volatile("s_waitcnt vmcnt(4)" ::: "memory"); }
  else        {              asm volatile("s_waitcnt vmcnt(0)" ::: "memory"); }
  __builtin_amdgcn_s_barrier();

  for (int kt = 0; kt <= qt; ++kt) {
    const int cur = kt & 1;
    f32x4 s[4];
#pragma unroll
    for (int nt = 0; nt < 4; ++nt) {
      f32x4 z = {};
#pragma unroll
      for (int ks = 0; ks < 2; ++ks) {
        int kof = (ks * 32 + (lane >> 4) * 8) ^ sw;
        bf16x8 kf = *(const bf16x8*)(&Ks[cur][(nt * 16 + (lane & 15)) * 64 + kof]);
        z = mfma16(qf[ks], kf, z);
      }
      s[nt] = z;
    }
    const bool diag = (kt == qt);
    float pm[4];
    bool ok = true;
#pragma unroll
    for (int r = 0; r < 4; ++r) {
      float mx = -3e38f;
#pragma unroll
      for (int nt = 0; nt < 4; ++nt) {
        float val = s[nt][r];
        if (diag && (kt * 64 + nt * 16 + (lane & 15)) > (rowb + r)) val = -3e38f;
        s[nt][r] = val;
        mx = fmaxf(mx, val);
      }
      mx = fmaxf(mx, __shfl_xor(mx, 1));
      mx = fmaxf(mx, __shfl_xor(mx, 2));
      mx = fmaxf(mx, __shfl_xor(mx, 4));
      mx = fmaxf(mx, __shfl_xor(mx, 8));
      pm[r] = mx;
      ok = ok && (mx <= mrow[r] + 11.5f);
    }
    if (!__all(ok)) {
#pragma unroll
      for (int r = 0; r < 4; ++r) {
        float mn = fmaxf(mrow[r], pm[r]);
        float al = fexp2(mrow[r] - mn);
        lrow[r] *= al;
#pragma unroll
        for (int d = 0; d < 4; ++d) o[d][r] *= al;
        mrow[r] = mn;
      }
    }
#pragma unroll
    for (int r = 0; r < 4; ++r) {
      float sum = 0.0f;
#pragma unroll
      for (int nt = 0; nt < 4; ++nt) {
        float pv = fexp2(s[nt][r] - mrow[r]);
        s[nt][r] = pv;
        sum += pv;
      }
      lrow[r] += sum;
    }
    // P -> wave-private LDS, XOR-swizzled: addr = qr*64 + (key ^ ((qr&7)*8))
#pragma unroll
    for (int nt = 0; nt < 4; ++nt)
#pragma unroll
      for (int r = 0; r < 4; ++r) {
        int qr = (lane >> 4) * 4 + r;
        Ps[wid][qr * 64 + ((nt * 16 + (lane & 15)) ^ ((qr & 7) * 8))] = f2bf(s[nt][r]);
      }
    // PV
#pragma unroll
    for (int ks = 0; ks < 2; ++ks) {
      int qr2 = lane & 15;
      bf16x8 pf = *(const bf16x8*)(&Ps[wid][qr2 * 64 + ((ks * 32 + (lane >> 4) * 8) ^ ((qr2 & 7) * 8))]);
      int kof = (ks * 32 + (lane >> 4) * 8) ^ sw;
#pragma unroll
      for (int d = 0; d < 4; ++d) {
        bf16x8 vf = *(const bf16x8*)(&Vs[cur][(d * 16 + (lane & 15)) * 64 + kof]);
        o[d] = mfma16(pf, vf, o[d]);
      }
    }
    __builtin_amdgcn_s_barrier();
    if (kt + 2 <= qt) {
      stage(kt + 2, cur);
      asm volatile("s_waitcnt vmcnt(4)" ::: "memory");
    } else if (kt + 1 <= qt) {
      asm volatile("s_waitcnt vmcnt(0)" ::: "memory");
    }
    __builtin_amdgcn_s_barrier();
  }
#pragma unroll
  for (int r = 0; r < 4; ++r) {
    lrow[r] += __shfl_xor(lrow[r], 1);
    lrow[r] += __shfl_xor(lrow[r], 2);
    lrow[r] += __shfl_xor(lrow[r], 4);
    lrow[r] += __shfl_xor(lrow[r], 8);
  }
#pragma unroll
  for (int d = 0; d < 4; ++d)
#pragma unroll
    for (int r = 0; r < 4; ++r) {
      float val = o[d][r] / lrow[r];
      ctx[((size_t)b * 2048 + (rowb + r)) * 1024 + hh * 64 + d * 16 + (lane & 15)] = f2bf(val);
    }
}

extern "C" void kernel_launch(void* const* d_in, const int* in_sizes, int n_in,
                              void* d_out, int out_size, void* d_ws, size_t ws_size,
                              hipStream_t stream) {
  (void)in_sizes; (void)n_in; (void)out_size; (void)ws_size;
  const float* in_f = (const float*)d_in[0];
  const int* pos    = (const int*)d_in[1];
  const float* q_w  = (const float*)d_in[2];
  const float* k_w  = (const float*)d_in[3];
  const float* v_w  = (const float*)d_in[4];
  const float* o_w  = (const float*)d_in[5];
  const float* ln1  = (const float*)d_in[6];
  const float* ln2  = (const float*)d_in[7];
  const float* w1   = (const float*)d_in[8];
  const float* w2   = (const float*)d_in[9];
  const float* w3   = (const float*)d_in[10];
  float* out = (float*)d_out;

  unsigned short* ws = (unsigned short*)d_ws;
  unsigned short* wb   = ws;
  unsigned short* wqkb = wb;
  unsigned short* wvb  = wb + 2097152;
  unsigned short* wob  = wb + 3145728;
  unsigned short* w1b  = wb + 4194304;
  unsigned short* w2b  = wb + 8388608;
  unsigned short* w3b  = wb + 12582912;
  unsigned short* xn   = ws + 16777216;
  unsigned short* qb   = ws + 20971520;
  unsigned short* kb   = ws + 25165824;   // must be qb + 4194304
  unsigned short* vb   = ws + 29360128;   // V^T [bh][64][2048]
  unsigned short* cx   = ws + 33554432;
  unsigned short* gb   = ws + 37748736;
  float* part          = (float*)(ws + 20971520);  // aliases qb..gb (dead by w2)
  unsigned short* hb   = ws + 54525952;

  CvtArgs ca;
  ca.src[0] = q_w; ca.src[1] = k_w; ca.src[2] = v_w; ca.src[3] = o_w;
  ca.src[4] = w1;  ca.src[5] = w2;  ca.src[6] = w3;
  ca.cum[0] = 0;        ca.cum[1] = 1048576;  ca.cum[2] = 2097152;  ca.cum[3] = 3145728;
  ca.cum[4] = 4194304;  ca.cum[5] = 8388608;  ca.cum[6] = 12582912; ca.cum[7] = 16777216;
  cvt_all<<<16384, 256, 0, stream>>>(ca, wb);

  rmsnorm_k<<<4096, 256, 0, stream>>>(in_f, ln1, xn);

  gemm8_qkv<<<192, 512, 0, stream>>>(xn, wqkb, wvb, qb, vb);

  rope2_k<<<16384, 256, 0, stream>>>(qb, kb, pos);

  attn_k<<<1024, 256, 0, stream>>>(qb, kb, vb, cx);

  gemm_wo<<<dim3(32, 8), 256, 0, stream>>>(cx, wob, out, in_f);

  rmsnorm_k<<<4096, 256, 0, stream>>>(out, ln2, xn);

  gemm8_k<3><<<256, 512, 0, stream>>>(xn, 1024, w1b, 1024, 16, 0, 16, gb, nullptr, nullptr, nullptr);
  gemm8_k<4><<<256, 512, 0, stream>>>(xn, 1024, w3b, 1024, 16, 0, 16, hb, nullptr, nullptr, gb);
  gemm8_k<5><<<dim3(64, 4), 512, 0, stream>>>(hb, 4096, w2b, 4096, 16, 1024, 16, nullptr, part, nullptr, nullptr);

  reduce_k<<<4096, 256, 0, stream>>>(out, part);
}